// Round 7
// baseline (235.744 us; speedup 1.0000x reference)
//
#include <hip/hip_runtime.h>
#include <hip/hip_bf16.h>
#include <stdint.h>

#define T_SEQ 2048
#define DIMSZ 1024
#define NH    16
#define HDIM  64
#define NBATCH 2
#define ATT_SCALE 0.12f

typedef __attribute__((ext_vector_type(8))) __bf16 bf16x8;
typedef __attribute__((ext_vector_type(4))) float f32x4;

#define GLOAD_LDS16(gp, lp)                                                            \
  __builtin_amdgcn_global_load_lds((const __attribute__((address_space(1))) void*)(gp),\
                                   (__attribute__((address_space(3))) void*)(lp),      \
                                   16, 0, 0)

__device__ __forceinline__ ushort f2bf(float f) {
  union { float f; uint32_t u; } v; v.f = f;
  uint32_t u = v.u;
  uint32_t r = (u + 0x7FFFu + ((u >> 16) & 1u)) >> 16;
  return (ushort)r;
}

__device__ __forceinline__ float bf2f(ushort h) {
  union { float f; uint32_t u; } v;
  v.u = ((uint32_t)h) << 16;
  return v.f;
}

// paired f32->bf16 (compiler fuses into v_cvt_pk_bf16_f32)
__device__ __forceinline__ uint32_t pk2(float a, float b) {
  union { __hip_bfloat162 h; uint32_t u; } cv;
  cv.h = __hip_bfloat162(__float2bfloat16(a), __float2bfloat16(b));
  return cv.u;
}

// ---------------- f32 -> bf16 convert (vectorized) ----------------
__global__ __launch_bounds__(256) void conv_bf16_k(const float* __restrict__ in,
                                                   ushort* __restrict__ out, int n) {
  int i = (blockIdx.x * 256 + threadIdx.x) * 4;
  if (i >= n) return;
  float4 v = *(const float4*)(in + i);
  ushort4 o;
  o.x = f2bf(v.x); o.y = f2bf(v.y); o.z = f2bf(v.z); o.w = f2bf(v.w);
  *(ushort4*)(out + i) = o;
}

// ---------------- RoPE tables: cos/sin (T x 32) ----------------
__global__ __launch_bounds__(256) void rope_tab_k(float* __restrict__ ctab,
                                                  float* __restrict__ stab) {
  int idx = blockIdx.x * 256 + threadIdx.x;  // t*32 + j
  if (idx >= T_SEQ * 32) return;
  int j = idx & 31, t = idx >> 5;
  float c = 1.f, s = 0.f;
  if (j < 16) {
    float inv = powf(1024.0f, -(float)j / 15.0f);  // (1/1024)^(j/15)
    float th = (float)t * inv;
    c = cosf(th);
    s = sinf(th);
  }
  ctab[idx] = c;
  stab[idx] = s;
}

// ---------------- bf16 GEMM: C(MxN) = A(MxK) * Bt(NxK)^T ----------------
#define BM 128
#define BN 128
#define BKS 64

template <typename OT>
__global__ __launch_bounds__(256) void gemm_bt_k(const ushort* __restrict__ A,
                                                 const ushort* __restrict__ Bt,
                                                 OT* __restrict__ C,
                                                 int M, int N, int K) {
  __shared__ __align__(16) ushort As[BM * BKS];
  __shared__ __align__(16) ushort Bs[BN * BKS];
  int tid = threadIdx.x;
  int wave = tid >> 6, lane = tid & 63;
  int lr = lane & 15, lg = lane >> 4;
  int m0 = blockIdx.x * BM, n0 = blockIdx.y * BN;
  int wm = (wave >> 1) * 64, wn = (wave & 1) * 64;

  f32x4 acc[4][4];
  for (int m = 0; m < 4; ++m)
    for (int n = 0; n < 4; ++n)
      acc[m][n] = (f32x4){0.f, 0.f, 0.f, 0.f};

  for (int k0 = 0; k0 < K; k0 += BKS) {
#pragma unroll
    for (int it = 0; it < 4; ++it) {
      int idx = it * 256 + tid;        // 16B chunk id, 1024 total
      int row = idx >> 3;              // 8 chunks per 64-elem row
      int col = (idx & 7) * 8;
      GLOAD_LDS16(A + (size_t)(m0 + row) * K + k0 + col, &As[idx * 8]);
      GLOAD_LDS16(Bt + (size_t)(n0 + row) * K + k0 + col, &Bs[idx * 8]);
    }
    __syncthreads();
#pragma unroll
    for (int kk = 0; kk < 2; ++kk) {
      bf16x8 af[4], bf[4];
#pragma unroll
      for (int m = 0; m < 4; ++m)
        af[m] = *(const bf16x8*)&As[(wm + m * 16 + lr) * BKS + kk * 32 + lg * 8];
#pragma unroll
      for (int n = 0; n < 4; ++n)
        bf[n] = *(const bf16x8*)&Bs[(wn + n * 16 + lr) * BKS + kk * 32 + lg * 8];
#pragma unroll
      for (int m = 0; m < 4; ++m)
#pragma unroll
        for (int n = 0; n < 4; ++n)
          acc[m][n] = __builtin_amdgcn_mfma_f32_16x16x32_bf16(af[m], bf[n], acc[m][n], 0, 0, 0);
    }
    __syncthreads();
  }
#pragma unroll
  for (int m = 0; m < 4; ++m)
#pragma unroll
    for (int n = 0; n < 4; ++n)
#pragma unroll
      for (int r = 0; r < 4; ++r) {
        int row = m0 + wm + m * 16 + lg * 4 + r;
        int col = n0 + wn + n * 16 + lr;
        if constexpr (sizeof(OT) == 2)
          C[(size_t)row * N + col] = (OT)f2bf(acc[m][n][r]);
        else
          C[(size_t)row * N + col] = (OT)acc[m][n][r];
      }
}

// ---------------- per-(b,t,h): RMSNorm + RoPE + v-mix (bf16 input) ----------------
// Q gets ATT_SCALE * log2(e) folded in so attention softmax runs in exp2 domain.
__global__ __launch_bounds__(256) void qkv_post_k(const ushort* __restrict__ QKVb,
                                                  const float* __restrict__ ve,
                                                  const float* __restrict__ lam,
                                                  const float* __restrict__ ctab,
                                                  const float* __restrict__ stab,
                                                  ushort* __restrict__ Qb,
                                                  ushort* __restrict__ Kb,
                                                  ushort* __restrict__ Vt) {
  int idx = blockIdx.x * 4 + (threadIdx.x >> 6);  // (b*T + t)*NH + h
  int lane = threadIdx.x & 63;
  int h = idx & (NH - 1);
  int bt = idx >> 4;
  int t = bt & (T_SEQ - 1);
  int b = bt >> 11;

  const ushort* base = QKVb + (size_t)bt * 3072 + h * HDIM + lane;
  float qv = bf2f(base[0]);
  float kv = bf2f(base[1024]);
  float vv = bf2f(base[2048]);

  float sq = qv * qv, sk = kv * kv, sv = vv * vv;
#pragma unroll
  for (int off = 1; off < 64; off <<= 1) {
    sq += __shfl_xor(sq, off);
    sk += __shfl_xor(sk, off);
    sv += __shfl_xor(sv, off);
  }
  qv *= rsqrtf(sq * (1.0f / 64.0f) + 1e-6f);
  kv *= rsqrtf(sk * (1.0f / 64.0f) + 1e-6f);
  vv *= rsqrtf(sv * (1.0f / 64.0f) + 1e-6f);

  int j = lane & 31;
  float c = ctab[t * 32 + j];
  float s = stab[t * 32 + j];
  float qo = __shfl_xor(qv, 32);
  float ko = __shfl_xor(kv, 32);
  float q2 = (lane < 32) ? (qv * c + qo * s) : (qv * c - qo * s);
  float k2 = (lane < 32) ? (kv * c + ko * s) : (kv * c - ko * s);
  float v2 = lam[0] * vv + lam[1] * ve[(size_t)bt * DIMSZ + h * HDIM + lane];

  q2 *= ATT_SCALE * 1.4426950408889634f;  // fold scale + log2(e) for exp2-domain softmax

  int bh = b * NH + h;
  Qb[((size_t)bh * T_SEQ + t) * HDIM + lane] = f2bf(q2);
  Kb[((size_t)bh * T_SEQ + t) * HDIM + lane] = f2bf(k2);
  Vt[((size_t)bh * HDIM + lane) * T_SEQ + t] = f2bf(v2);
}

// ---------------- flash attention: 8-wave blocks, SIMD-intrinsic balance ----------------
// Grid (bh=32, pair=16), 512 threads = 8 waves. Wave w: q-tile = (w<4 ? pair : 31-pair),
// strip = w&3. HW maps wave w -> SIMD w%4, so each SIMD gets one (pair+1)-iter wave and
// one (32-pair)-iter wave = 33 iters, balanced BY CONSTRUCTION. 2 blocks/CU -> 4 waves/SIMD
// (2x TLP vs R6). Static-shift softmax: no cross-lane ops in loop, no barriers anywhere.
__global__ __launch_bounds__(512, 4) void attn_k(const ushort* __restrict__ Q,
                                                 const ushort* __restrict__ K,
                                                 const ushort* __restrict__ Vt,
                                                 ushort* __restrict__ Y) {
  int bh = blockIdx.x;    // 0..31 -> linear%8 = bh%8 (XCD L2 locality)
  int pair = blockIdx.y;  // 0..15
  int wid = threadIdx.x >> 6, lane = threadIdx.x & 63;
  int lr = lane & 15, lg = lane >> 4;
  int b = bh >> 4, h = bh & 15;

  __shared__ __align__(16) ushort Plds[8][16][72];  // per-wave P tile

  const ushort* Kbh = K + (size_t)bh * T_SEQ * HDIM;
  const ushort* Vbh = Vt + (size_t)bh * HDIM * T_SEQ;

  int qb = (wid < 4) ? pair : (31 - pair);
  int strip = wid & 3;
  int r0 = qb * 64 + strip * 16;
  int nkv = qb + 1;

  const ushort* Qbase = Q + ((size_t)bh * T_SEQ + r0) * HDIM;
  bf16x8 aq[2];
#pragma unroll
  for (int kk = 0; kk < 2; ++kk)
    aq[kk] = *(const bf16x8*)(Qbase + (size_t)lr * HDIM + kk * 32 + lg * 8);

  f32x4 o[4];
#pragma unroll
  for (int n = 0; n < 4; ++n) o[n] = (f32x4){0.f, 0.f, 0.f, 0.f};
  float lrow = 0.f;  // lane-partial row sum; reduced once in epilogue

  // preload K block 0
  bf16x8 kc[8];
#pragma unroll
  for (int kk = 0; kk < 2; ++kk)
#pragma unroll
    for (int n = 0; n < 4; ++n)
      kc[kk * 4 + n] = *(const bf16x8*)(Kbh + (size_t)(n * 16 + lr) * HDIM + kk * 32 + lg * 8);

  for (int kb = 0; kb < nkv; ++kb) {
    int s0 = kb * 64;
    // S^T = K . Q^T : lane holds S[q=r0+lr][key = s0 + n*16 + lg*4 + r]
    f32x4 s[4];
#pragma unroll
    for (int n = 0; n < 4; ++n) {
      f32x4 a = (f32x4){0.f, 0.f, 0.f, 0.f};
#pragma unroll
      for (int kk = 0; kk < 2; ++kk)
        a = __builtin_amdgcn_mfma_f32_16x16x32_bf16(kc[kk * 4 + n], aq[kk], a, 0, 0, 0);
      s[n] = a;
    }
    // guarded prefetch of next K block (WAR-safe; hidden under exp2 + PV)
    if (kb + 1 < nkv) {
      const ushort* Kn = Kbh + (size_t)(s0 + 64) * HDIM;
#pragma unroll
      for (int kk = 0; kk < 2; ++kk)
#pragma unroll
        for (int n = 0; n < 4; ++n)
          kc[kk * 4 + n] = *(const bf16x8*)(Kn + (size_t)(n * 16 + lr) * HDIM + kk * 32 + lg * 8);
    }
    // issue V loads now; exp2/pack hides their latency
    bf16x8 vv[8];
#pragma unroll
    for (int kk = 0; kk < 2; ++kk)
#pragma unroll
      for (int n = 0; n < 4; ++n)
        vv[kk * 4 + n] = *(const bf16x8*)(Vbh + (size_t)(n * 16 + lr) * T_SEQ + s0 + kk * 32 + lg * 8);

    // causal mask on the diagonal block
    if (kb == nkv - 1) {
      int qrow = r0 + lr;
      int kb0 = s0 + lg * 4;
#pragma unroll
      for (int n = 0; n < 4; ++n)
#pragma unroll
        for (int r = 0; r < 4; ++r)
          if (kb0 + n * 16 + r > qrow) s[n][r] = -1e30f;
    }
    // P = exp2(S)  (static shift: |arg| <= 11.08 after RMSNorm); lane-partial sum; pack
    float psum = 0.f;
#pragma unroll
    for (int n = 0; n < 4; ++n) {
      float p0 = exp2f(s[n][0]), p1 = exp2f(s[n][1]);
      float p2 = exp2f(s[n][2]), p3 = exp2f(s[n][3]);
      psum += (p0 + p1) + (p2 + p3);
      uint2 w;
      w.x = pk2(p0, p1);
      w.y = pk2(p2, p3);
      *(uint2*)&Plds[wid][lr][n * 16 + lg * 4] = w;
    }
    lrow += psum;
    // PV: O^T += V^T . P^T
#pragma unroll
    for (int kk = 0; kk < 2; ++kk) {
      bf16x8 ap = *(const bf16x8*)&Plds[wid][lr][kk * 32 + lg * 8];
#pragma unroll
      for (int n = 0; n < 4; ++n)
        o[n] = __builtin_amdgcn_mfma_f32_16x16x32_bf16(vv[kk * 4 + n], ap, o[n], 0, 0, 0);
    }
  }
  // epilogue: complete row sum across lg groups, normalize, write
  lrow += __shfl_xor(lrow, 16);
  lrow += __shfl_xor(lrow, 32);
  float inv = 1.0f / lrow;
  int row = r0 + lr;
#pragma unroll
  for (int n = 0; n < 4; ++n) {
    uint2 w;
    w.x = pk2(o[n][0] * inv, o[n][1] * inv);
    w.y = pk2(o[n][2] * inv, o[n][3] * inv);
    *(uint2*)&Y[((size_t)b * T_SEQ + row) * DIMSZ + h * HDIM + n * 16 + lg * 4] = w;
  }
}

// ---------------- launch ----------------
extern "C" void kernel_launch(void* const* d_in, const int* in_sizes, int n_in,
                              void* d_out, int out_size, void* d_ws, size_t ws_size,
                              hipStream_t stream) {
  const float* x   = (const float*)d_in[0];
  const float* ve  = (const float*)d_in[1];
  const float* lam = (const float*)d_in[2];
  const float* w   = (const float*)d_in[4];  // (4, 1024, 1024)
  float* out = (float*)d_out;

  char* ws = (char*)d_ws;
  const size_t NTOK = (size_t)NBATCH * T_SEQ;          // 4096
  const size_t nX = NTOK * DIMSZ;                      // 4,194,304
  const size_t nW = 4ull * DIMSZ * DIMSZ;              // 4,194,304

  ushort* Xb   = (ushort*)(ws);                        // 8 MB  @ 0
  ushort* Wb   = (ushort*)(ws + 8388608);              // 8 MB  @ 8M
  ushort* QKVb = (ushort*)(ws + 16777216);             // 24 MB @ 16M (bf16)
  ushort* Qb   = (ushort*)(ws + 50331648);             // 8 MB  @ 48M
  ushort* Kb   = (ushort*)(ws + 58720256);             // 8 MB  @ 56M
  ushort* Vt   = (ushort*)(ws + 67108864);             // 8 MB  @ 64M
  ushort* Yb   = (ushort*)(ws + 75497472);             // 8 MB  @ 72M
  float*  ctab = (float*)(ws + 83886080);              // 256 KB @ 80M
  float*  stab = (float*)(ws + 84148224);              // 256 KB

  conv_bf16_k<<<(int)(nX / 4 / 256), 256, 0, stream>>>(x, Xb, (int)nX);
  conv_bf16_k<<<(int)(nW / 4 / 256), 256, 0, stream>>>(w, Wb, (int)nW);
  rope_tab_k<<<(T_SEQ * 32) / 256, 256, 0, stream>>>(ctab, stab);

  // QKV: (4096 x 3072) = Xb (4096x1024) @ Wb[0:3072]^T, bf16 out
  gemm_bt_k<ushort><<<dim3(4096 / BM, 3072 / BN), 256, 0, stream>>>(Xb, Wb, QKVb, 4096, 3072, 1024);

  qkv_post_k<<<(int)(NTOK * NH / 4), 256, 0, stream>>>(QKVb, ve, lam, ctab, stab, Qb, Kb, Vt);

  attn_k<<<dim3(NBATCH * NH, 16), 512, 0, stream>>>(Qb, Kb, Vt, Yb);

  // out: (4096 x 1024) = Yb @ W3^T, f32 straight to d_out
  gemm_bt_k<float><<<dim3(4096 / BM, 1024 / BN), 256, 0, stream>>>(Yb, Wb + 3ull * DIMSZ * DIMSZ, out, 4096, 1024, 1024);
}

// Round 8
// 157.563 us; speedup vs baseline: 1.4962x; 1.4962x over previous
//
#include <hip/hip_runtime.h>
#include <hip/hip_bf16.h>
#include <stdint.h>

#define T_SEQ 2048
#define DIMSZ 1024
#define NH    16
#define HDIM  64
#define NBATCH 2
#define KVB   64
#define ATT_SCALE 0.12f

typedef __attribute__((ext_vector_type(8))) __bf16 bf16x8;
typedef __attribute__((ext_vector_type(4))) float f32x4;

#define GLOAD_LDS16(gp, lp)                                                            \
  __builtin_amdgcn_global_load_lds((const __attribute__((address_space(1))) void*)(gp),\
                                   (__attribute__((address_space(3))) void*)(lp),      \
                                   16, 0, 0)

__device__ __forceinline__ ushort f2bf(float f) {
  union { float f; uint32_t u; } v; v.f = f;
  uint32_t u = v.u;
  uint32_t r = (u + 0x7FFFu + ((u >> 16) & 1u)) >> 16;
  return (ushort)r;
}

__device__ __forceinline__ float bf2f(ushort h) {
  union { float f; uint32_t u; } v;
  v.u = ((uint32_t)h) << 16;
  return v.f;
}

// paired f32->bf16 (compiler fuses into v_cvt_pk_bf16_f32)
__device__ __forceinline__ uint32_t pk2(float a, float b) {
  union { __hip_bfloat162 h; uint32_t u; } cv;
  cv.h = __hip_bfloat162(__float2bfloat16(a), __float2bfloat16(b));
  return cv.u;
}

// ---------------- f32 -> bf16 convert (vectorized) ----------------
__global__ __launch_bounds__(256) void conv_bf16_k(const float* __restrict__ in,
                                                   ushort* __restrict__ out, int n) {
  int i = (blockIdx.x * 256 + threadIdx.x) * 4;
  if (i >= n) return;
  float4 v = *(const float4*)(in + i);
  ushort4 o;
  o.x = f2bf(v.x); o.y = f2bf(v.y); o.z = f2bf(v.z); o.w = f2bf(v.w);
  *(ushort4*)(out + i) = o;
}

// ---------------- RoPE tables: cos/sin (T x 32) ----------------
__global__ __launch_bounds__(256) void rope_tab_k(float* __restrict__ ctab,
                                                  float* __restrict__ stab) {
  int idx = blockIdx.x * 256 + threadIdx.x;  // t*32 + j
  if (idx >= T_SEQ * 32) return;
  int j = idx & 31, t = idx >> 5;
  float c = 1.f, s = 0.f;
  if (j < 16) {
    float inv = powf(1024.0f, -(float)j / 15.0f);  // (1/1024)^(j/15)
    float th = (float)t * inv;
    c = cosf(th);
    s = sinf(th);
  }
  ctab[idx] = c;
  stab[idx] = s;
}

// ---------------- bf16 GEMM: C(MxN) = A(MxK) * Bt(NxK)^T ----------------
#define BM 128
#define BN 128
#define BKS 64

template <typename OT>
__global__ __launch_bounds__(256) void gemm_bt_k(const ushort* __restrict__ A,
                                                 const ushort* __restrict__ Bt,
                                                 OT* __restrict__ C,
                                                 int M, int N, int K) {
  __shared__ __align__(16) ushort As[BM * BKS];
  __shared__ __align__(16) ushort Bs[BN * BKS];
  int tid = threadIdx.x;
  int wave = tid >> 6, lane = tid & 63;
  int lr = lane & 15, lg = lane >> 4;
  int m0 = blockIdx.x * BM, n0 = blockIdx.y * BN;
  int wm = (wave >> 1) * 64, wn = (wave & 1) * 64;

  f32x4 acc[4][4];
  for (int m = 0; m < 4; ++m)
    for (int n = 0; n < 4; ++n)
      acc[m][n] = (f32x4){0.f, 0.f, 0.f, 0.f};

  for (int k0 = 0; k0 < K; k0 += BKS) {
#pragma unroll
    for (int it = 0; it < 4; ++it) {
      int idx = it * 256 + tid;        // 16B chunk id, 1024 total
      int row = idx >> 3;              // 8 chunks per 64-elem row
      int col = (idx & 7) * 8;
      GLOAD_LDS16(A + (size_t)(m0 + row) * K + k0 + col, &As[idx * 8]);
      GLOAD_LDS16(Bt + (size_t)(n0 + row) * K + k0 + col, &Bs[idx * 8]);
    }
    __syncthreads();
#pragma unroll
    for (int kk = 0; kk < 2; ++kk) {
      bf16x8 af[4], bf[4];
#pragma unroll
      for (int m = 0; m < 4; ++m)
        af[m] = *(const bf16x8*)&As[(wm + m * 16 + lr) * BKS + kk * 32 + lg * 8];
#pragma unroll
      for (int n = 0; n < 4; ++n)
        bf[n] = *(const bf16x8*)&Bs[(wn + n * 16 + lr) * BKS + kk * 32 + lg * 8];
#pragma unroll
      for (int m = 0; m < 4; ++m)
#pragma unroll
        for (int n = 0; n < 4; ++n)
          acc[m][n] = __builtin_amdgcn_mfma_f32_16x16x32_bf16(af[m], bf[n], acc[m][n], 0, 0, 0);
    }
    __syncthreads();
  }
#pragma unroll
  for (int m = 0; m < 4; ++m)
#pragma unroll
    for (int n = 0; n < 4; ++n)
#pragma unroll
      for (int r = 0; r < 4; ++r) {
        int row = m0 + wm + m * 16 + lg * 4 + r;
        int col = n0 + wn + n * 16 + lr;
        if constexpr (sizeof(OT) == 2)
          C[(size_t)row * N + col] = (OT)f2bf(acc[m][n][r]);
        else
          C[(size_t)row * N + col] = (OT)acc[m][n][r];
      }
}

// ---------------- per-(b,t,h): RMSNorm + RoPE + v-mix (bf16 input) ----------------
// Q gets ATT_SCALE * log2(e) folded in so attention softmax runs in exp2 domain.
__global__ __launch_bounds__(256) void qkv_post_k(const ushort* __restrict__ QKVb,
                                                  const float* __restrict__ ve,
                                                  const float* __restrict__ lam,
                                                  const float* __restrict__ ctab,
                                                  const float* __restrict__ stab,
                                                  ushort* __restrict__ Qb,
                                                  ushort* __restrict__ Kb,
                                                  ushort* __restrict__ Vt) {
  int idx = blockIdx.x * 4 + (threadIdx.x >> 6);  // (b*T + t)*NH + h
  int lane = threadIdx.x & 63;
  int h = idx & (NH - 1);
  int bt = idx >> 4;
  int t = bt & (T_SEQ - 1);
  int b = bt >> 11;

  const ushort* base = QKVb + (size_t)bt * 3072 + h * HDIM + lane;
  float qv = bf2f(base[0]);
  float kv = bf2f(base[1024]);
  float vv = bf2f(base[2048]);

  float sq = qv * qv, sk = kv * kv, sv = vv * vv;
#pragma unroll
  for (int off = 1; off < 64; off <<= 1) {
    sq += __shfl_xor(sq, off);
    sk += __shfl_xor(sk, off);
    sv += __shfl_xor(sv, off);
  }
  qv *= rsqrtf(sq * (1.0f / 64.0f) + 1e-6f);
  kv *= rsqrtf(sk * (1.0f / 64.0f) + 1e-6f);
  vv *= rsqrtf(sv * (1.0f / 64.0f) + 1e-6f);

  int j = lane & 31;
  float c = ctab[t * 32 + j];
  float s = stab[t * 32 + j];
  float qo = __shfl_xor(qv, 32);
  float ko = __shfl_xor(kv, 32);
  float q2 = (lane < 32) ? (qv * c + qo * s) : (qv * c - qo * s);
  float k2 = (lane < 32) ? (kv * c + ko * s) : (kv * c - ko * s);
  float v2 = lam[0] * vv + lam[1] * ve[(size_t)bt * DIMSZ + h * HDIM + lane];

  q2 *= ATT_SCALE * 1.4426950408889634f;  // fold scale + log2(e) for exp2-domain softmax

  int bh = b * NH + h;
  Qb[((size_t)bh * T_SEQ + t) * HDIM + lane] = f2bf(q2);
  Kb[((size_t)bh * T_SEQ + t) * HDIM + lane] = f2bf(k2);
  Vt[((size_t)bh * HDIM + lane) * T_SEQ + t] = f2bf(v2);
}

// ---------------- flash attention: LDS-shared K/V, dual-tile blocks ----------------
// Theory: R2-R7 invariance (126-130us over occupancy 20-31%) = shared-resource
// saturation: 1.08 GB of per-wave L2 fragment traffic (4x redundant per strip).
// Fix: block = 512 thr / 8 waves handles q-tiles {pair} (waves 0-3) AND {31-pair}
// (waves 4-7); barrier-synced kb loop 0..31-pair stages each K/V tile ONCE into
// double-buffered LDS via global_load_lds (8x VMEM cut). Stage issued BEFORE
// compute (T14); __syncthreads (compiler emits vmcnt(0)+lgkmcnt(0)) fences.
// LDS frag reads at 128B row stride would be 16-way bank conflicts -> XOR-swizzle
// chunk^(row&7), implemented by pre-swizzling the GLOBAL source (linear LDS dest,
// m173 pattern) and XORing the read column. Balance: block wall = 32-pair;
// heavy-first dispatch (y=pair) gives ~constant ~49 wall-iters/CU.
__global__ __launch_bounds__(512, 4) void attn_k(const ushort* __restrict__ Q,
                                                 const ushort* __restrict__ K,
                                                 const ushort* __restrict__ Vt,
                                                 ushort* __restrict__ Y) {
  int bh = blockIdx.x;    // 0..31 -> dispatch id % 8 = bh % 8 (XCD L2 locality)
  int pair = blockIdx.y;  // 0..15, heavy (pair=0 -> 32 tiles) first
  int tid = threadIdx.x;
  int wid = tid >> 6, lane = tid & 63;
  int lr = lane & 15, lg = lane >> 4;
  int b = bh >> 4, h = bh & 15;

  int NT = 32 - pair;                    // staged KV tiles: kb = 0..NT-1
  int grp = wid >> 2;                    // 0 -> tile pair, 1 -> tile 31-pair
  int myqb = grp ? (31 - pair) : pair;
  int mylast = grp ? (NT - 1) : pair;    // my diagonal (and last active) iter
  int strip = wid & 3;
  int r0 = myqb * 64 + strip * 16;

  __shared__ __align__(16) ushort Kl[2][KVB * HDIM];   // 2 x 8 KB
  __shared__ __align__(16) ushort Vl[2][KVB * HDIM];   // 2 x 8 KB ([d=64][key=64])
  __shared__ __align__(16) ushort Plds[8][16][72];

  const ushort* Kbh = K + (size_t)bh * T_SEQ * HDIM;
  const ushort* Vbh = Vt + (size_t)bh * HDIM * T_SEQ;

  // staging: thread t -> LDS (row = t>>3, 16B-chunk = t&7); source pre-swizzled
  int srow = tid >> 3, schunk = tid & 7;
  int sel = ((schunk ^ (srow & 7)) << 3);                 // element offset in 64-elem row
  const ushort* ksrc = Kbh + (size_t)srow * HDIM + sel;   // + kb*KVB*HDIM
  const ushort* vsrc = Vbh + (size_t)srow * T_SEQ + sel;  // + kb*KVB
  int ldst = wid << 9;                                    // wave-uniform LDS base (elems)

  // Q fragments (global, read once)
  const ushort* Qbase = Q + ((size_t)bh * T_SEQ + r0) * HDIM;
  bf16x8 aq[2];
#pragma unroll
  for (int kk = 0; kk < 2; ++kk)
    aq[kk] = *(const bf16x8*)(Qbase + (size_t)lr * HDIM + kk * 32 + lg * 8);

  // swizzled fragment column offsets (element units)
  int fcol[2];
  fcol[0] = ((0 + lg) ^ (lr & 7)) << 3;
  fcol[1] = ((4 + lg) ^ (lr & 7)) << 3;

  f32x4 o[4];
#pragma unroll
  for (int n = 0; n < 4; ++n) o[n] = (f32x4){0.f, 0.f, 0.f, 0.f};
  float lrow = 0.f;

  // prologue: stage tile 0 into buffer 0
  GLOAD_LDS16(ksrc, &Kl[0][ldst]);
  GLOAD_LDS16(vsrc, &Vl[0][ldst]);
  __syncthreads();

  int cur = 0;
  for (int kb = 0; kb < NT; ++kb) {
    // issue next tile's staging first (latency hides under compute)
    if (kb + 1 < NT) {
      GLOAD_LDS16(ksrc + (size_t)(kb + 1) * KVB * HDIM, &Kl[cur ^ 1][ldst]);
      GLOAD_LDS16(vsrc + (kb + 1) * KVB, &Vl[cur ^ 1][ldst]);
    }
    if (kb <= mylast) {
      const ushort* Kc = &Kl[cur][0];
      const ushort* Vc = &Vl[cur][0];
      // S^T = K . Q^T : lane holds S[q=r0+lr][key = kb*64 + n*16 + lg*4 + r]
      f32x4 s[4];
#pragma unroll
      for (int n = 0; n < 4; ++n) {
        f32x4 a = (f32x4){0.f, 0.f, 0.f, 0.f};
        bf16x8 kf0 = *(const bf16x8*)&Kc[(n * 16 + lr) * HDIM + fcol[0]];
        a = __builtin_amdgcn_mfma_f32_16x16x32_bf16(kf0, aq[0], a, 0, 0, 0);
        bf16x8 kf1 = *(const bf16x8*)&Kc[(n * 16 + lr) * HDIM + fcol[1]];
        a = __builtin_amdgcn_mfma_f32_16x16x32_bf16(kf1, aq[1], a, 0, 0, 0);
        s[n] = a;
      }
      // causal mask on my diagonal tile
      if (kb == mylast) {
        int qrow = r0 + lr;
        int kb0 = kb * KVB + lg * 4;
#pragma unroll
        for (int n = 0; n < 4; ++n)
#pragma unroll
          for (int r = 0; r < 4; ++r)
            if (kb0 + n * 16 + r > qrow) s[n][r] = -1e30f;
      }
      // P = exp2(S) (static shift: |arg| <= 11.08 after RMSNorm); lane-partial sum
      float psum = 0.f;
#pragma unroll
      for (int n = 0; n < 4; ++n) {
        float p0 = exp2f(s[n][0]), p1 = exp2f(s[n][1]);
        float p2 = exp2f(s[n][2]), p3 = exp2f(s[n][3]);
        psum += (p0 + p1) + (p2 + p3);
        uint2 w;
        w.x = pk2(p0, p1);
        w.y = pk2(p2, p3);
        *(uint2*)&Plds[wid][lr][n * 16 + lg * 4] = w;
      }
      lrow += psum;
      // PV: O^T += V^T . P^T
#pragma unroll
      for (int kk = 0; kk < 2; ++kk) {
        bf16x8 ap = *(const bf16x8*)&Plds[wid][lr][kk * 32 + lg * 8];
#pragma unroll
        for (int n = 0; n < 4; ++n) {
          bf16x8 vf = *(const bf16x8*)&Vc[(n * 16 + lr) * HDIM + fcol[kk]];
          o[n] = __builtin_amdgcn_mfma_f32_16x16x32_bf16(vf, ap, o[n], 0, 0, 0);
        }
      }
    }
    __syncthreads();  // staging landed (vmcnt 0) + buf[cur] consumed by all
    cur ^= 1;
  }
  // epilogue: complete row sum across lg groups, normalize, write
  lrow += __shfl_xor(lrow, 16);
  lrow += __shfl_xor(lrow, 32);
  float inv = 1.0f / lrow;
  int row = r0 + lr;
#pragma unroll
  for (int n = 0; n < 4; ++n) {
    uint2 w;
    w.x = pk2(o[n][0] * inv, o[n][1] * inv);
    w.y = pk2(o[n][2] * inv, o[n][3] * inv);
    *(uint2*)&Y[((size_t)b * T_SEQ + row) * DIMSZ + h * HDIM + n * 16 + lg * 4] = w;
  }
}

// ---------------- launch ----------------
extern "C" void kernel_launch(void* const* d_in, const int* in_sizes, int n_in,
                              void* d_out, int out_size, void* d_ws, size_t ws_size,
                              hipStream_t stream) {
  const float* x   = (const float*)d_in[0];
  const float* ve  = (const float*)d_in[1];
  const float* lam = (const float*)d_in[2];
  const float* w   = (const float*)d_in[4];  // (4, 1024, 1024)
  float* out = (float*)d_out;

  char* ws = (char*)d_ws;
  const size_t NTOK = (size_t)NBATCH * T_SEQ;          // 4096
  const size_t nX = NTOK * DIMSZ;                      // 4,194,304
  const size_t nW = 4ull * DIMSZ * DIMSZ;              // 4,194,304

  ushort* Xb   = (ushort*)(ws);                        // 8 MB  @ 0
  ushort* Wb   = (ushort*)(ws + 8388608);              // 8 MB  @ 8M
  ushort* QKVb = (ushort*)(ws + 16777216);             // 24 MB @ 16M (bf16)
  ushort* Qb   = (ushort*)(ws + 50331648);             // 8 MB  @ 48M
  ushort* Kb   = (ushort*)(ws + 58720256);             // 8 MB  @ 56M
  ushort* Vt   = (ushort*)(ws + 67108864);             // 8 MB  @ 64M
  ushort* Yb   = (ushort*)(ws + 75497472);             // 8 MB  @ 72M
  float*  ctab = (float*)(ws + 83886080);              // 256 KB @ 80M
  float*  stab = (float*)(ws + 84148224);              // 256 KB

  conv_bf16_k<<<(int)(nX / 4 / 256), 256, 0, stream>>>(x, Xb, (int)nX);
  conv_bf16_k<<<(int)(nW / 4 / 256), 256, 0, stream>>>(w, Wb, (int)nW);
  rope_tab_k<<<(T_SEQ * 32) / 256, 256, 0, stream>>>(ctab, stab);

  // QKV: (4096 x 3072) = Xb (4096x1024) @ Wb[0:3072]^T, bf16 out
  gemm_bt_k<ushort><<<dim3(4096 / BM, 3072 / BN), 256, 0, stream>>>(Xb, Wb, QKVb, 4096, 3072, 1024);

  qkv_post_k<<<(int)(NTOK * NH / 4), 256, 0, stream>>>(QKVb, ve, lam, ctab, stab, Qb, Kb, Vt);

  attn_k<<<dim3(NBATCH * NH, 16), 512, 0, stream>>>(Qb, Kb, Vt, Yb);

  // out: (4096 x 1024) = Yb @ W3^T, f32 straight to d_out
  gemm_bt_k<float><<<dim3(4096 / BM, 1024 / BN), 256, 0, stream>>>(Yb, Wb + 3ull * DIMSZ * DIMSZ, out, 4096, 1024, 1024);
}

// Round 9
// 152.204 us; speedup vs baseline: 1.5489x; 1.0352x over previous
//
#include <hip/hip_runtime.h>
#include <hip/hip_bf16.h>
#include <stdint.h>

#define T_SEQ 2048
#define DIMSZ 1024
#define NH    16
#define HDIM  64
#define NBATCH 2
#define KVB   64
#define ATT_SCALE 0.12f
#define QSCALE (0.12f * 1.4426950408889634f)

typedef __attribute__((ext_vector_type(8))) __bf16 bf16x8;
typedef __attribute__((ext_vector_type(4))) float f32x4;

#define GLOAD_LDS16(gp, lp)                                                            \
  __builtin_amdgcn_global_load_lds((const __attribute__((address_space(1))) void*)(gp),\
                                   (__attribute__((address_space(3))) void*)(lp),      \
                                   16, 0, 0)

__device__ __forceinline__ ushort f2bf(float f) {
  union { float f; uint32_t u; } v; v.f = f;
  uint32_t u = v.u;
  uint32_t r = (u + 0x7FFFu + ((u >> 16) & 1u)) >> 16;
  return (ushort)r;
}

__device__ __forceinline__ float bf2f(ushort h) {
  union { float f; uint32_t u; } v;
  v.u = ((uint32_t)h) << 16;
  return v.f;
}

// paired f32->bf16 (compiler fuses into v_cvt_pk_bf16_f32)
__device__ __forceinline__ uint32_t pk2(float a, float b) {
  union { __hip_bfloat162 h; uint32_t u; } cv;
  cv.h = __hip_bfloat162(__float2bfloat16(a), __float2bfloat16(b));
  return cv.u;
}

// ---------------- f32 -> bf16 convert (vectorized) ----------------
__global__ __launch_bounds__(256) void conv_bf16_k(const float* __restrict__ in,
                                                   ushort* __restrict__ out, int n) {
  int i = (blockIdx.x * 256 + threadIdx.x) * 4;
  if (i >= n) return;
  float4 v = *(const float4*)(in + i);
  ushort4 o;
  o.x = f2bf(v.x); o.y = f2bf(v.y); o.z = f2bf(v.z); o.w = f2bf(v.w);
  *(ushort4*)(out + i) = o;
}

// ---------------- RoPE tables: cos/sin (T x 32) ----------------
__global__ __launch_bounds__(256) void rope_tab_k(float* __restrict__ ctab,
                                                  float* __restrict__ stab) {
  int idx = blockIdx.x * 256 + threadIdx.x;  // t*32 + j
  if (idx >= T_SEQ * 32) return;
  int j = idx & 31, t = idx >> 5;
  float c = 1.f, s = 0.f;
  if (j < 16) {
    float inv = powf(1024.0f, -(float)j / 15.0f);  // (1/1024)^(j/15)
    float th = (float)t * inv;
    c = cosf(th);
    s = sinf(th);
  }
  ctab[idx] = c;
  stab[idx] = s;
}

// ---------------- bf16 GEMM: C(MxN) = A(MxK) * Bt(NxK)^T (plain, for out-proj) ----
#define BM 128
#define BN 128
#define BKS 64

template <typename OT>
__global__ __launch_bounds__(256) void gemm_bt_k(const ushort* __restrict__ A,
                                                 const ushort* __restrict__ Bt,
                                                 OT* __restrict__ C,
                                                 int M, int N, int K) {
  __shared__ __align__(16) ushort As[BM * BKS];
  __shared__ __align__(16) ushort Bs[BN * BKS];
  int tid = threadIdx.x;
  int wave = tid >> 6, lane = tid & 63;
  int lr = lane & 15, lg = lane >> 4;
  int m0 = blockIdx.x * BM, n0 = blockIdx.y * BN;
  int wm = (wave >> 1) * 64, wn = (wave & 1) * 64;

  f32x4 acc[4][4];
  for (int m = 0; m < 4; ++m)
    for (int n = 0; n < 4; ++n)
      acc[m][n] = (f32x4){0.f, 0.f, 0.f, 0.f};

  for (int k0 = 0; k0 < K; k0 += BKS) {
#pragma unroll
    for (int it = 0; it < 4; ++it) {
      int idx = it * 256 + tid;        // 16B chunk id, 1024 total
      int row = idx >> 3;              // 8 chunks per 64-elem row
      int col = (idx & 7) * 8;
      GLOAD_LDS16(A + (size_t)(m0 + row) * K + k0 + col, &As[idx * 8]);
      GLOAD_LDS16(Bt + (size_t)(n0 + row) * K + k0 + col, &Bs[idx * 8]);
    }
    __syncthreads();
#pragma unroll
    for (int kk = 0; kk < 2; ++kk) {
      bf16x8 af[4], bf[4];
#pragma unroll
      for (int m = 0; m < 4; ++m)
        af[m] = *(const bf16x8*)&As[(wm + m * 16 + lr) * BKS + kk * 32 + lg * 8];
#pragma unroll
      for (int n = 0; n < 4; ++n)
        bf[n] = *(const bf16x8*)&Bs[(wn + n * 16 + lr) * BKS + kk * 32 + lg * 8];
#pragma unroll
      for (int m = 0; m < 4; ++m)
#pragma unroll
        for (int n = 0; n < 4; ++n)
          acc[m][n] = __builtin_amdgcn_mfma_f32_16x16x32_bf16(af[m], bf[n], acc[m][n], 0, 0, 0);
    }
    __syncthreads();
  }
#pragma unroll
  for (int m = 0; m < 4; ++m)
#pragma unroll
    for (int n = 0; n < 4; ++n)
#pragma unroll
      for (int r = 0; r < 4; ++r) {
        int row = m0 + wm + m * 16 + lg * 4 + r;
        int col = n0 + wn + n * 16 + lr;
        if constexpr (sizeof(OT) == 2)
          C[(size_t)row * N + col] = (OT)f2bf(acc[m][n][r]);
        else
          C[(size_t)row * N + col] = (OT)acc[m][n][r];
      }
}

// ---------------- QKV GEMM with fused RMSNorm + RoPE + v-mix epilogue ----------------
// Same main loop as gemm_bt_k (N=3072, K=1024). Epilogue exploits the C layout:
// each wave owns 64 output cols = ONE head; a row's 64 dims live in the 16 lanes
// sharing lg (4 vals each) -> RMSNorm = in-lane sq-sum + shfl_xor{1,2,4,8};
// RoPE pairs (d,d+32) = regs (n,n+2) in-lane. Writes Q,K (bh,t,d) and Vt (bh,d,t)
// directly; Q gets ATT_SCALE*log2(e) folded (exp2-domain softmax downstream).
__global__ __launch_bounds__(256) void gemm_qkv_k(const ushort* __restrict__ A,
                                                  const ushort* __restrict__ Bt,
                                                  const float* __restrict__ ve,
                                                  const float* __restrict__ lam,
                                                  const float* __restrict__ ctab,
                                                  const float* __restrict__ stab,
                                                  ushort* __restrict__ Qb,
                                                  ushort* __restrict__ Kb,
                                                  ushort* __restrict__ Vt) {
  const int K = DIMSZ, N = 3 * DIMSZ;
  __shared__ __align__(16) ushort As[BM * BKS];
  __shared__ __align__(16) ushort Bs[BN * BKS];
  int tid = threadIdx.x;
  int wave = tid >> 6, lane = tid & 63;
  int lr = lane & 15, lg = lane >> 4;
  int m0 = blockIdx.x * BM, n0 = blockIdx.y * BN;
  int wm = (wave >> 1) * 64, wn = (wave & 1) * 64;

  f32x4 acc[4][4];
  for (int m = 0; m < 4; ++m)
    for (int n = 0; n < 4; ++n)
      acc[m][n] = (f32x4){0.f, 0.f, 0.f, 0.f};

  for (int k0 = 0; k0 < K; k0 += BKS) {
#pragma unroll
    for (int it = 0; it < 4; ++it) {
      int idx = it * 256 + tid;
      int row = idx >> 3;
      int col = (idx & 7) * 8;
      GLOAD_LDS16(A + (size_t)(m0 + row) * K + k0 + col, &As[idx * 8]);
      GLOAD_LDS16(Bt + (size_t)(n0 + row) * K + k0 + col, &Bs[idx * 8]);
    }
    __syncthreads();
#pragma unroll
    for (int kk = 0; kk < 2; ++kk) {
      bf16x8 af[4], bf[4];
#pragma unroll
      for (int m = 0; m < 4; ++m)
        af[m] = *(const bf16x8*)&As[(wm + m * 16 + lr) * BKS + kk * 32 + lg * 8];
#pragma unroll
      for (int n = 0; n < 4; ++n)
        bf[n] = *(const bf16x8*)&Bs[(wn + n * 16 + lr) * BKS + kk * 32 + lg * 8];
#pragma unroll
      for (int m = 0; m < 4; ++m)
#pragma unroll
        for (int n = 0; n < 4; ++n)
          acc[m][n] = __builtin_amdgcn_mfma_f32_16x16x32_bf16(af[m], bf[n], acc[m][n], 0, 0, 0);
    }
    __syncthreads();
  }

  // fused epilogue
  int sec = n0 >> 10;                       // 0=Q, 1=K, 2=V (block-uniform)
  int h = ((n0 & 1023) + wn) >> 6;          // head (wave-uniform)
  float l0 = lam[0], l1 = lam[1];

#pragma unroll
  for (int m = 0; m < 4; ++m)
#pragma unroll
    for (int r = 0; r < 4; ++r) {
      int row = m0 + wm + m * 16 + lg * 4 + r;  // token id 0..4095
      int t = row & (T_SEQ - 1);
      int b = row >> 11;
      int bh = b * NH + h;
      float v0 = acc[m][0][r], v1 = acc[m][1][r], v2 = acc[m][2][r], v3 = acc[m][3][r];
      // RMSNorm over the 64-dim head row (16 lanes share lg; xor<16 stays in-group)
      float ss = v0 * v0 + v1 * v1 + v2 * v2 + v3 * v3;
      ss += __shfl_xor(ss, 1);
      ss += __shfl_xor(ss, 2);
      ss += __shfl_xor(ss, 4);
      ss += __shfl_xor(ss, 8);
      float rinv = rsqrtf(ss * (1.0f / 64.0f) + 1e-6f);
      v0 *= rinv; v1 *= rinv; v2 *= rinv; v3 *= rinv;
      if (sec < 2) {
        // RoPE: d pairs (lr, 32+lr) = (v0,v2), (16+lr, 48+lr) = (v1,v3)
        const float* ct = ctab + t * 32;
        const float* st = stab + t * 32;
        float c0 = ct[lr], s0 = st[lr], c1 = ct[16 + lr], s1 = st[16 + lr];
        float y0 = v0 * c0 + v2 * s0;
        float y2 = v2 * c0 - v0 * s0;
        float y1 = v1 * c1 + v3 * s1;
        float y3 = v3 * c1 - v1 * s1;
        if (sec == 0) { y0 *= QSCALE; y1 *= QSCALE; y2 *= QSCALE; y3 *= QSCALE; }
        ushort* dst = (sec == 0 ? Qb : Kb) + ((size_t)bh * T_SEQ + t) * HDIM;
        dst[lr] = f2bf(y0);
        dst[16 + lr] = f2bf(y1);
        dst[32 + lr] = f2bf(y2);
        dst[48 + lr] = f2bf(y3);
      } else {
        const float* vs = ve + ((size_t)(b * T_SEQ + t)) * DIMSZ + h * HDIM;
        float y0 = l0 * v0 + l1 * vs[lr];
        float y1 = l0 * v1 + l1 * vs[16 + lr];
        float y2 = l0 * v2 + l1 * vs[32 + lr];
        float y3 = l0 * v3 + l1 * vs[48 + lr];
        ushort* dst = Vt + (size_t)bh * HDIM * T_SEQ + t;
        dst[(size_t)(lr) * T_SEQ] = f2bf(y0);
        dst[(size_t)(16 + lr) * T_SEQ] = f2bf(y1);
        dst[(size_t)(32 + lr) * T_SEQ] = f2bf(y2);
        dst[(size_t)(48 + lr) * T_SEQ] = f2bf(y3);
      }
    }
}

// ---------------- flash attention: LDS-shared K/V, dual-tile blocks (R8, unchanged) ----
__global__ __launch_bounds__(512, 4) void attn_k(const ushort* __restrict__ Q,
                                                 const ushort* __restrict__ K,
                                                 const ushort* __restrict__ Vt,
                                                 ushort* __restrict__ Y) {
  int bh = blockIdx.x;    // 0..31 -> dispatch id % 8 = bh % 8 (XCD L2 locality)
  int pair = blockIdx.y;  // 0..15, heavy (pair=0 -> 32 tiles) first
  int tid = threadIdx.x;
  int wid = tid >> 6, lane = tid & 63;
  int lr = lane & 15, lg = lane >> 4;
  int b = bh >> 4, h = bh & 15;

  int NT = 32 - pair;                    // staged KV tiles: kb = 0..NT-1
  int grp = wid >> 2;                    // 0 -> tile pair, 1 -> tile 31-pair
  int myqb = grp ? (31 - pair) : pair;
  int mylast = grp ? (NT - 1) : pair;    // my diagonal (and last active) iter
  int strip = wid & 3;
  int r0 = myqb * 64 + strip * 16;

  __shared__ __align__(16) ushort Kl[2][KVB * HDIM];   // 2 x 8 KB
  __shared__ __align__(16) ushort Vl[2][KVB * HDIM];   // 2 x 8 KB ([d=64][key=64])
  __shared__ __align__(16) ushort Plds[8][16][72];

  const ushort* Kbh = K + (size_t)bh * T_SEQ * HDIM;
  const ushort* Vbh = Vt + (size_t)bh * HDIM * T_SEQ;

  // staging: thread t -> LDS (row = t>>3, 16B-chunk = t&7); source pre-swizzled
  int srow = tid >> 3, schunk = tid & 7;
  int sel = ((schunk ^ (srow & 7)) << 3);                 // element offset in 64-elem row
  const ushort* ksrc = Kbh + (size_t)srow * HDIM + sel;   // + kb*KVB*HDIM
  const ushort* vsrc = Vbh + (size_t)srow * T_SEQ + sel;  // + kb*KVB
  int ldst = wid << 9;                                    // wave-uniform LDS base (elems)

  // Q fragments (global, read once)
  const ushort* Qbase = Q + ((size_t)bh * T_SEQ + r0) * HDIM;
  bf16x8 aq[2];
#pragma unroll
  for (int kk = 0; kk < 2; ++kk)
    aq[kk] = *(const bf16x8*)(Qbase + (size_t)lr * HDIM + kk * 32 + lg * 8);

  // swizzled fragment column offsets (element units)
  int fcol[2];
  fcol[0] = ((0 + lg) ^ (lr & 7)) << 3;
  fcol[1] = ((4 + lg) ^ (lr & 7)) << 3;

  f32x4 o[4];
#pragma unroll
  for (int n = 0; n < 4; ++n) o[n] = (f32x4){0.f, 0.f, 0.f, 0.f};
  float lrow = 0.f;

  // prologue: stage tile 0 into buffer 0
  GLOAD_LDS16(ksrc, &Kl[0][ldst]);
  GLOAD_LDS16(vsrc, &Vl[0][ldst]);
  __syncthreads();

  int cur = 0;
  for (int kb = 0; kb < NT; ++kb) {
    // issue next tile's staging first (latency hides under compute)
    if (kb + 1 < NT) {
      GLOAD_LDS16(ksrc + (size_t)(kb + 1) * KVB * HDIM, &Kl[cur ^ 1][ldst]);
      GLOAD_LDS16(vsrc + (kb + 1) * KVB, &Vl[cur ^ 1][ldst]);
    }
    if (kb <= mylast) {
      const ushort* Kc = &Kl[cur][0];
      const ushort* Vc = &Vl[cur][0];
      // S^T = K . Q^T : lane holds S[q=r0+lr][key = kb*64 + n*16 + lg*4 + r]
      f32x4 s[4];
#pragma unroll
      for (int n = 0; n < 4; ++n) {
        f32x4 a = (f32x4){0.f, 0.f, 0.f, 0.f};
        bf16x8 kf0 = *(const bf16x8*)&Kc[(n * 16 + lr) * HDIM + fcol[0]];
        a = __builtin_amdgcn_mfma_f32_16x16x32_bf16(kf0, aq[0], a, 0, 0, 0);
        bf16x8 kf1 = *(const bf16x8*)&Kc[(n * 16 + lr) * HDIM + fcol[1]];
        a = __builtin_amdgcn_mfma_f32_16x16x32_bf16(kf1, aq[1], a, 0, 0, 0);
        s[n] = a;
      }
      // causal mask on my diagonal tile
      if (kb == mylast) {
        int qrow = r0 + lr;
        int kb0 = kb * KVB + lg * 4;
#pragma unroll
        for (int n = 0; n < 4; ++n)
#pragma unroll
          for (int r = 0; r < 4; ++r)
            if (kb0 + n * 16 + r > qrow) s[n][r] = -1e30f;
      }
      // P = exp2(S) (static shift: |arg| <= 11.08 after RMSNorm); lane-partial sum
      float psum = 0.f;
#pragma unroll
      for (int n = 0; n < 4; ++n) {
        float p0 = exp2f(s[n][0]), p1 = exp2f(s[n][1]);
        float p2 = exp2f(s[n][2]), p3 = exp2f(s[n][3]);
        psum += (p0 + p1) + (p2 + p3);
        uint2 w;
        w.x = pk2(p0, p1);
        w.y = pk2(p2, p3);
        *(uint2*)&Plds[wid][lr][n * 16 + lg * 4] = w;
      }
      lrow += psum;
      // PV: O^T += V^T . P^T
#pragma unroll
      for (int kk = 0; kk < 2; ++kk) {
        bf16x8 ap = *(const bf16x8*)&Plds[wid][lr][kk * 32 + lg * 8];
#pragma unroll
        for (int n = 0; n < 4; ++n) {
          bf16x8 vf = *(const bf16x8*)&Vc[(n * 16 + lr) * HDIM + fcol[kk]];
          o[n] = __builtin_amdgcn_mfma_f32_16x16x32_bf16(vf, ap, o[n], 0, 0, 0);
        }
      }
    }
    __syncthreads();  // staging landed (vmcnt 0) + buf[cur] consumed by all
    cur ^= 1;
  }
  // epilogue: complete row sum across lg groups, normalize, write
  lrow += __shfl_xor(lrow, 16);
  lrow += __shfl_xor(lrow, 32);
  float inv = 1.0f / lrow;
  int row = r0 + lr;
#pragma unroll
  for (int n = 0; n < 4; ++n) {
    uint2 w;
    w.x = pk2(o[n][0] * inv, o[n][1] * inv);
    w.y = pk2(o[n][2] * inv, o[n][3] * inv);
    *(uint2*)&Y[((size_t)b * T_SEQ + row) * DIMSZ + h * HDIM + n * 16 + lg * 4] = w;
  }
}

// ---------------- launch ----------------
extern "C" void kernel_launch(void* const* d_in, const int* in_sizes, int n_in,
                              void* d_out, int out_size, void* d_ws, size_t ws_size,
                              hipStream_t stream) {
  const float* x   = (const float*)d_in[0];
  const float* ve  = (const float*)d_in[1];
  const float* lam = (const float*)d_in[2];
  const float* w   = (const float*)d_in[4];  // (4, 1024, 1024)
  float* out = (float*)d_out;

  char* ws = (char*)d_ws;
  const size_t NTOK = (size_t)NBATCH * T_SEQ;          // 4096
  const size_t nX = NTOK * DIMSZ;                      // 4,194,304
  const size_t nW = 4ull * DIMSZ * DIMSZ;              // 4,194,304

  ushort* Xb   = (ushort*)(ws);                        // 8 MB  @ 0
  ushort* Wb   = (ushort*)(ws + 8388608);              // 8 MB  @ 8M
  ushort* Qb   = (ushort*)(ws + 16777216);             // 8 MB  @ 16M
  ushort* Kb   = (ushort*)(ws + 25165824);             // 8 MB  @ 24M
  ushort* Vt   = (ushort*)(ws + 33554432);             // 8 MB  @ 32M
  ushort* Yb   = (ushort*)(ws + 41943040);             // 8 MB  @ 40M
  float*  ctab = (float*)(ws + 50331648);              // 256 KB @ 48M
  float*  stab = (float*)(ws + 50593792);              // 256 KB

  conv_bf16_k<<<(int)(nX / 4 / 256), 256, 0, stream>>>(x, Xb, (int)nX);
  conv_bf16_k<<<(int)(nW / 4 / 256), 256, 0, stream>>>(w, Wb, (int)nW);
  rope_tab_k<<<(T_SEQ * 32) / 256, 256, 0, stream>>>(ctab, stab);

  // QKV GEMM (4096 x 3072 x 1024) with fused RMSNorm/RoPE/v-mix epilogue
  gemm_qkv_k<<<dim3(4096 / BM, 3072 / BN), 256, 0, stream>>>(Xb, Wb, ve, lam, ctab, stab,
                                                             Qb, Kb, Vt);

  attn_k<<<dim3(NBATCH * NH, 16), 512, 0, stream>>>(Qb, Kb, Vt, Yb);

  // out: (4096 x 1024) = Yb @ W3^T, f32 straight to d_out
  gemm_bt_k<float><<<dim3(4096 / BM, 1024 / BN), 256, 0, stream>>>(Yb, Wb + 3ull * DIMSZ * DIMSZ, out, 4096, 1024, 1024);
}

// Round 10
// 137.509 us; speedup vs baseline: 1.7144x; 1.1069x over previous
//
#include <hip/hip_runtime.h>
#include <hip/hip_bf16.h>
#include <stdint.h>

#define T_SEQ 2048
#define DIMSZ 1024
#define NH    16
#define HDIM  64
#define NBATCH 2
#define KVB   64
#define ATT_SCALE 0.12f
#define QSCALE (0.12f * 1.4426950408889634f)

typedef __attribute__((ext_vector_type(8))) __bf16 bf16x8;
typedef __attribute__((ext_vector_type(8))) ushort u16x8;
typedef __attribute__((ext_vector_type(4))) float f32x4;

#define GLOAD_LDS16(gp, lp)                                                            \
  __builtin_amdgcn_global_load_lds((const __attribute__((address_space(1))) void*)(gp),\
                                   (__attribute__((address_space(3))) void*)(lp),      \
                                   16, 0, 0)

__device__ __forceinline__ ushort f2bf(float f) {
  union { float f; uint32_t u; } v; v.f = f;
  uint32_t u = v.u;
  uint32_t r = (u + 0x7FFFu + ((u >> 16) & 1u)) >> 16;
  return (ushort)r;
}

__device__ __forceinline__ float bf2f(ushort h) {
  union { float f; uint32_t u; } v;
  v.u = ((uint32_t)h) << 16;
  return v.f;
}

// paired f32->bf16 (compiler fuses into v_cvt_pk_bf16_f32)
__device__ __forceinline__ uint32_t pk2(float a, float b) {
  union { __hip_bfloat162 h; uint32_t u; } cv;
  cv.h = __hip_bfloat162(__float2bfloat16(a), __float2bfloat16(b));
  return cv.u;
}

// ---------------- f32 -> bf16 convert (vectorized) ----------------
__global__ __launch_bounds__(256) void conv_bf16_k(const float* __restrict__ in,
                                                   ushort* __restrict__ out, int n) {
  int i = (blockIdx.x * 256 + threadIdx.x) * 4;
  if (i >= n) return;
  float4 v = *(const float4*)(in + i);
  ushort4 o;
  o.x = f2bf(v.x); o.y = f2bf(v.y); o.z = f2bf(v.z); o.w = f2bf(v.w);
  *(ushort4*)(out + i) = o;
}

// ---------------- RoPE tables: cos/sin (T x 32) ----------------
__global__ __launch_bounds__(256) void rope_tab_k(float* __restrict__ ctab,
                                                  float* __restrict__ stab) {
  int idx = blockIdx.x * 256 + threadIdx.x;  // t*32 + j
  if (idx >= T_SEQ * 32) return;
  int j = idx & 31, t = idx >> 5;
  float c = 1.f, s = 0.f;
  if (j < 16) {
    float inv = powf(1024.0f, -(float)j / 15.0f);  // (1/1024)^(j/15)
    float th = (float)t * inv;
    c = cosf(th);
    s = sinf(th);
  }
  ctab[idx] = c;
  stab[idx] = s;
}

// ---------------- bf16 GEMM: C(MxN) = A(MxK) * Bt(NxK)^T (plain, for out-proj) ----
#define BM 128
#define BN 128
#define BKS 64

template <typename OT>
__global__ __launch_bounds__(256) void gemm_bt_k(const ushort* __restrict__ A,
                                                 const ushort* __restrict__ Bt,
                                                 OT* __restrict__ C,
                                                 int M, int N, int K) {
  __shared__ __align__(16) ushort As[BM * BKS];
  __shared__ __align__(16) ushort Bs[BN * BKS];
  int tid = threadIdx.x;
  int wave = tid >> 6, lane = tid & 63;
  int lr = lane & 15, lg = lane >> 4;
  int m0 = blockIdx.x * BM, n0 = blockIdx.y * BN;
  int wm = (wave >> 1) * 64, wn = (wave & 1) * 64;

  f32x4 acc[4][4];
  for (int m = 0; m < 4; ++m)
    for (int n = 0; n < 4; ++n)
      acc[m][n] = (f32x4){0.f, 0.f, 0.f, 0.f};

  for (int k0 = 0; k0 < K; k0 += BKS) {
#pragma unroll
    for (int it = 0; it < 4; ++it) {
      int idx = it * 256 + tid;        // 16B chunk id, 1024 total
      int row = idx >> 3;              // 8 chunks per 64-elem row
      int col = (idx & 7) * 8;
      GLOAD_LDS16(A + (size_t)(m0 + row) * K + k0 + col, &As[idx * 8]);
      GLOAD_LDS16(Bt + (size_t)(n0 + row) * K + k0 + col, &Bs[idx * 8]);
    }
    __syncthreads();
#pragma unroll
    for (int kk = 0; kk < 2; ++kk) {
      bf16x8 af[4], bf[4];
#pragma unroll
      for (int m = 0; m < 4; ++m)
        af[m] = *(const bf16x8*)&As[(wm + m * 16 + lr) * BKS + kk * 32 + lg * 8];
#pragma unroll
      for (int n = 0; n < 4; ++n)
        bf[n] = *(const bf16x8*)&Bs[(wn + n * 16 + lr) * BKS + kk * 32 + lg * 8];
#pragma unroll
      for (int m = 0; m < 4; ++m)
#pragma unroll
        for (int n = 0; n < 4; ++n)
          acc[m][n] = __builtin_amdgcn_mfma_f32_16x16x32_bf16(af[m], bf[n], acc[m][n], 0, 0, 0);
    }
    __syncthreads();
  }
#pragma unroll
  for (int m = 0; m < 4; ++m)
#pragma unroll
    for (int n = 0; n < 4; ++n)
#pragma unroll
      for (int r = 0; r < 4; ++r) {
        int row = m0 + wm + m * 16 + lg * 4 + r;
        int col = n0 + wn + n * 16 + lr;
        if constexpr (sizeof(OT) == 2)
          C[(size_t)row * N + col] = (OT)f2bf(acc[m][n][r]);
        else
          C[(size_t)row * N + col] = (OT)acc[m][n][r];
      }
}

// ---------------- QKV GEMM with fused epilogue v2 (token-ownership) ----------------
// Main loop identical to gemm_bt_k. Epilogue: wave's 64x64 C-tile -> bf16 in an 8KB
// LDS quarter (reusing As/Bs, [token][dim] with chunk-XOR swizzle) -> each lane owns
// ONE token row (64 dims): RMSNorm fully in-lane (no shuffles), RoPE in-lane,
// Q/K stores 8x dwordx4/lane, V stores 128B-coalesced (64 consecutive tokens/wave).
__global__ __launch_bounds__(256) void gemm_qkv_k(const ushort* __restrict__ A,
                                                  const ushort* __restrict__ Bt,
                                                  const float* __restrict__ ve,
                                                  const float* __restrict__ lam,
                                                  const float* __restrict__ ctab,
                                                  const float* __restrict__ stab,
                                                  ushort* __restrict__ Qb,
                                                  ushort* __restrict__ Kb,
                                                  ushort* __restrict__ Vt) {
  const int K = DIMSZ, N = 3 * DIMSZ;
  __shared__ __align__(16) ushort As[BM * BKS];
  __shared__ __align__(16) ushort Bs[BN * BKS];
  int tid = threadIdx.x;
  int wave = tid >> 6, lane = tid & 63;
  int lr = lane & 15, lg = lane >> 4;
  int m0 = blockIdx.x * BM, n0 = blockIdx.y * BN;
  int wm = (wave >> 1) * 64, wn = (wave & 1) * 64;

  f32x4 acc[4][4];
  for (int m = 0; m < 4; ++m)
    for (int n = 0; n < 4; ++n)
      acc[m][n] = (f32x4){0.f, 0.f, 0.f, 0.f};

  for (int k0 = 0; k0 < K; k0 += BKS) {
#pragma unroll
    for (int it = 0; it < 4; ++it) {
      int idx = it * 256 + tid;
      int row = idx >> 3;
      int col = (idx & 7) * 8;
      GLOAD_LDS16(A + (size_t)(m0 + row) * K + k0 + col, &As[idx * 8]);
      GLOAD_LDS16(Bt + (size_t)(n0 + row) * K + k0 + col, &Bs[idx * 8]);
    }
    __syncthreads();
#pragma unroll
    for (int kk = 0; kk < 2; ++kk) {
      bf16x8 af[4], bf[4];
#pragma unroll
      for (int m = 0; m < 4; ++m)
        af[m] = *(const bf16x8*)&As[(wm + m * 16 + lr) * BKS + kk * 32 + lg * 8];
#pragma unroll
      for (int n = 0; n < 4; ++n)
        bf[n] = *(const bf16x8*)&Bs[(wn + n * 16 + lr) * BKS + kk * 32 + lg * 8];
#pragma unroll
      for (int m = 0; m < 4; ++m)
#pragma unroll
        for (int n = 0; n < 4; ++n)
          acc[m][n] = __builtin_amdgcn_mfma_f32_16x16x32_bf16(af[m], bf[n], acc[m][n], 0, 0, 0);
    }
    __syncthreads();
  }

  // ---- epilogue v2: per-wave LDS transpose to token-ownership ----
  int sec = n0 >> 10;                   // 0=Q, 1=K, 2=V (block-uniform)
  int h = ((n0 & 1023) + wn) >> 6;      // head (wave-uniform)
  // 8KB quarter per wave, reusing As/Bs (dead after final barrier)
  ushort* Tl = (wave < 2 ? As : Bs) + (wave & 1) * 4096;

  // write fragments as bf16: [token][dim], dim-chunk XOR-swizzled by (token&7)
#pragma unroll
  for (int m = 0; m < 4; ++m)
#pragma unroll
    for (int n = 0; n < 4; ++n)
#pragma unroll
      for (int r = 0; r < 4; ++r) {
        int tl = m * 16 + lg * 4 + r;
        int d = n * 16 + lr;
        Tl[tl * 64 + ((((d >> 3) ^ (tl & 7)) << 3) | (d & 7))] = f2bf(acc[m][n][r]);
      }

  // each lane reads its own token row (8 swizzled b128 reads)
  int tl = lane;
  float xv[64];
#pragma unroll
  for (int j = 0; j < 8; ++j) {
    u16x8 rw = *(const u16x8*)&Tl[tl * 64 + ((j ^ (tl & 7)) << 3)];
#pragma unroll
    for (int e = 0; e < 8; ++e) xv[j * 8 + e] = bf2f((ushort)rw[e]);
  }

  // RMSNorm in-lane
  float ss = 0.f;
#pragma unroll
  for (int i = 0; i < 64; ++i) ss += xv[i] * xv[i];
  float rinv = rsqrtf(ss * (1.0f / 64.0f) + 1e-6f);
#pragma unroll
  for (int i = 0; i < 64; ++i) xv[i] *= rinv;

  int row = m0 + wm + tl;               // token id 0..4095
  int t = row & (T_SEQ - 1);
  int bb = row >> 11;
  int bh = bb * NH + h;

  if (sec < 2) {
    // RoPE in-lane: pairs (j, j+32), table nonzero only for j<16
    float4 c4[4], s4[4];
    const float4* cp = (const float4*)(ctab + t * 32);
    const float4* sp = (const float4*)(stab + t * 32);
#pragma unroll
    for (int j = 0; j < 4; ++j) { c4[j] = cp[j]; s4[j] = sp[j]; }
    float cs[16], sn[16];
#pragma unroll
    for (int j = 0; j < 4; ++j) {
      cs[j * 4 + 0] = c4[j].x; cs[j * 4 + 1] = c4[j].y; cs[j * 4 + 2] = c4[j].z; cs[j * 4 + 3] = c4[j].w;
      sn[j * 4 + 0] = s4[j].x; sn[j * 4 + 1] = s4[j].y; sn[j * 4 + 2] = s4[j].z; sn[j * 4 + 3] = s4[j].w;
    }
#pragma unroll
    for (int j = 0; j < 16; ++j) {
      float a = xv[j], bv = xv[j + 32];
      xv[j] = a * cs[j] + bv * sn[j];
      xv[j + 32] = bv * cs[j] - a * sn[j];
    }
    float sc = (sec == 0) ? QSCALE : 1.0f;
    uint32_t ww[32];
#pragma unroll
    for (int p = 0; p < 32; ++p) ww[p] = pk2(xv[2 * p] * sc, xv[2 * p + 1] * sc);
    ushort* dst = (sec == 0 ? Qb : Kb) + ((size_t)bh * T_SEQ + t) * HDIM;
#pragma unroll
    for (int p = 0; p < 8; ++p) {
      uint4 wq = make_uint4(ww[4 * p], ww[4 * p + 1], ww[4 * p + 2], ww[4 * p + 3]);
      *((uint4*)dst + p) = wq;
    }
  } else {
    // v-mix: ve row (coalesced 16B/lane), then 64 fully-coalesced 2B stores
    float l0 = lam[0], l1 = lam[1];
    const float4* vp = (const float4*)(ve + ((size_t)(bb * T_SEQ + t)) * DIMSZ + h * HDIM);
#pragma unroll
    for (int j = 0; j < 16; ++j) {
      float4 vv4 = vp[j];
      xv[j * 4 + 0] = l0 * xv[j * 4 + 0] + l1 * vv4.x;
      xv[j * 4 + 1] = l0 * xv[j * 4 + 1] + l1 * vv4.y;
      xv[j * 4 + 2] = l0 * xv[j * 4 + 2] + l1 * vv4.z;
      xv[j * 4 + 3] = l0 * xv[j * 4 + 3] + l1 * vv4.w;
    }
    ushort* dst = Vt + (size_t)bh * HDIM * T_SEQ + t;
#pragma unroll
    for (int i = 0; i < 64; ++i)
      dst[(size_t)i * T_SEQ] = f2bf(xv[i]);
  }
}

// ---------------- flash attention: LDS-shared K/V, dual-tile blocks (unchanged) ----
__global__ __launch_bounds__(512, 4) void attn_k(const ushort* __restrict__ Q,
                                                 const ushort* __restrict__ K,
                                                 const ushort* __restrict__ Vt,
                                                 ushort* __restrict__ Y) {
  int bh = blockIdx.x;    // 0..31 -> dispatch id % 8 = bh % 8 (XCD L2 locality)
  int pair = blockIdx.y;  // 0..15, heavy (pair=0 -> 32 tiles) first
  int tid = threadIdx.x;
  int wid = tid >> 6, lane = tid & 63;
  int lr = lane & 15, lg = lane >> 4;
  int b = bh >> 4, h = bh & 15;

  int NT = 32 - pair;                    // staged KV tiles: kb = 0..NT-1
  int grp = wid >> 2;                    // 0 -> tile pair, 1 -> tile 31-pair
  int myqb = grp ? (31 - pair) : pair;
  int mylast = grp ? (NT - 1) : pair;    // my diagonal (and last active) iter
  int strip = wid & 3;
  int r0 = myqb * 64 + strip * 16;

  __shared__ __align__(16) ushort Kl[2][KVB * HDIM];   // 2 x 8 KB
  __shared__ __align__(16) ushort Vl[2][KVB * HDIM];   // 2 x 8 KB ([d=64][key=64])
  __shared__ __align__(16) ushort Plds[8][16][72];

  const ushort* Kbh = K + (size_t)bh * T_SEQ * HDIM;
  const ushort* Vbh = Vt + (size_t)bh * HDIM * T_SEQ;

  // staging: thread t -> LDS (row = t>>3, 16B-chunk = t&7); source pre-swizzled
  int srow = tid >> 3, schunk = tid & 7;
  int sel = ((schunk ^ (srow & 7)) << 3);                 // element offset in 64-elem row
  const ushort* ksrc = Kbh + (size_t)srow * HDIM + sel;   // + kb*KVB*HDIM
  const ushort* vsrc = Vbh + (size_t)srow * T_SEQ + sel;  // + kb*KVB
  int ldst = wid << 9;                                    // wave-uniform LDS base (elems)

  // Q fragments (global, read once)
  const ushort* Qbase = Q + ((size_t)bh * T_SEQ + r0) * HDIM;
  bf16x8 aq[2];
#pragma unroll
  for (int kk = 0; kk < 2; ++kk)
    aq[kk] = *(const bf16x8*)(Qbase + (size_t)lr * HDIM + kk * 32 + lg * 8);

  // swizzled fragment column offsets (element units)
  int fcol[2];
  fcol[0] = ((0 + lg) ^ (lr & 7)) << 3;
  fcol[1] = ((4 + lg) ^ (lr & 7)) << 3;

  f32x4 o[4];
#pragma unroll
  for (int n = 0; n < 4; ++n) o[n] = (f32x4){0.f, 0.f, 0.f, 0.f};
  float lrow = 0.f;

  // prologue: stage tile 0 into buffer 0
  GLOAD_LDS16(ksrc, &Kl[0][ldst]);
  GLOAD_LDS16(vsrc, &Vl[0][ldst]);
  __syncthreads();

  int cur = 0;
  for (int kb = 0; kb < NT; ++kb) {
    // issue next tile's staging first (latency hides under compute)
    if (kb + 1 < NT) {
      GLOAD_LDS16(ksrc + (size_t)(kb + 1) * KVB * HDIM, &Kl[cur ^ 1][ldst]);
      GLOAD_LDS16(vsrc + (kb + 1) * KVB, &Vl[cur ^ 1][ldst]);
    }
    if (kb <= mylast) {
      const ushort* Kc = &Kl[cur][0];
      const ushort* Vc = &Vl[cur][0];
      // S^T = K . Q^T : lane holds S[q=r0+lr][key = kb*64 + n*16 + lg*4 + r]
      f32x4 s[4];
#pragma unroll
      for (int n = 0; n < 4; ++n) {
        f32x4 a = (f32x4){0.f, 0.f, 0.f, 0.f};
        bf16x8 kf0 = *(const bf16x8*)&Kc[(n * 16 + lr) * HDIM + fcol[0]];
        a = __builtin_amdgcn_mfma_f32_16x16x32_bf16(kf0, aq[0], a, 0, 0, 0);
        bf16x8 kf1 = *(const bf16x8*)&Kc[(n * 16 + lr) * HDIM + fcol[1]];
        a = __builtin_amdgcn_mfma_f32_16x16x32_bf16(kf1, aq[1], a, 0, 0, 0);
        s[n] = a;
      }
      // causal mask on my diagonal tile
      if (kb == mylast) {
        int qrow = r0 + lr;
        int kb0 = kb * KVB + lg * 4;
#pragma unroll
        for (int n = 0; n < 4; ++n)
#pragma unroll
          for (int r = 0; r < 4; ++r)
            if (kb0 + n * 16 + r > qrow) s[n][r] = -1e30f;
      }
      // P = exp2(S) (static shift: |arg| <= 11.08 after RMSNorm); lane-partial sum
      float psum = 0.f;
#pragma unroll
      for (int n = 0; n < 4; ++n) {
        float p0 = exp2f(s[n][0]), p1 = exp2f(s[n][1]);
        float p2 = exp2f(s[n][2]), p3 = exp2f(s[n][3]);
        psum += (p0 + p1) + (p2 + p3);
        uint2 w;
        w.x = pk2(p0, p1);
        w.y = pk2(p2, p3);
        *(uint2*)&Plds[wid][lr][n * 16 + lg * 4] = w;
      }
      lrow += psum;
      // PV: O^T += V^T . P^T
#pragma unroll
      for (int kk = 0; kk < 2; ++kk) {
        bf16x8 ap = *(const bf16x8*)&Plds[wid][lr][kk * 32 + lg * 8];
#pragma unroll
        for (int n = 0; n < 4; ++n) {
          bf16x8 vf = *(const bf16x8*)&Vc[(n * 16 + lr) * HDIM + fcol[kk]];
          o[n] = __builtin_amdgcn_mfma_f32_16x16x32_bf16(vf, ap, o[n], 0, 0, 0);
        }
      }
    }
    __syncthreads();  // staging landed (vmcnt 0) + buf[cur] consumed by all
    cur ^= 1;
  }
  // epilogue: complete row sum across lg groups, normalize, write
  lrow += __shfl_xor(lrow, 16);
  lrow += __shfl_xor(lrow, 32);
  float inv = 1.0f / lrow;
  int row = r0 + lr;
#pragma unroll
  for (int n = 0; n < 4; ++n) {
    uint2 w;
    w.x = pk2(o[n][0] * inv, o[n][1] * inv);
    w.y = pk2(o[n][2] * inv, o[n][3] * inv);
    *(uint2*)&Y[((size_t)b * T_SEQ + row) * DIMSZ + h * HDIM + n * 16 + lg * 4] = w;
  }
}

// ---------------- launch ----------------
extern "C" void kernel_launch(void* const* d_in, const int* in_sizes, int n_in,
                              void* d_out, int out_size, void* d_ws, size_t ws_size,
                              hipStream_t stream) {
  const float* x   = (const float*)d_in[0];
  const float* ve  = (const float*)d_in[1];
  const float* lam = (const float*)d_in[2];
  const float* w   = (const float*)d_in[4];  // (4, 1024, 1024)
  float* out = (float*)d_out;

  char* ws = (char*)d_ws;
  const size_t NTOK = (size_t)NBATCH * T_SEQ;          // 4096
  const size_t nX = NTOK * DIMSZ;                      // 4,194,304
  const size_t nW = 4ull * DIMSZ * DIMSZ;              // 4,194,304

  ushort* Xb   = (ushort*)(ws);                        // 8 MB  @ 0
  ushort* Wb   = (ushort*)(ws + 8388608);              // 8 MB  @ 8M
  ushort* Qb   = (ushort*)(ws + 16777216);             // 8 MB  @ 16M
  ushort* Kb   = (ushort*)(ws + 25165824);             // 8 MB  @ 24M
  ushort* Vt   = (ushort*)(ws + 33554432);             // 8 MB  @ 32M
  ushort* Yb   = (ushort*)(ws + 41943040);             // 8 MB  @ 40M
  float*  ctab = (float*)(ws + 50331648);              // 256 KB @ 48M
  float*  stab = (float*)(ws + 50593792);              // 256 KB

  conv_bf16_k<<<(int)(nX / 4 / 256), 256, 0, stream>>>(x, Xb, (int)nX);
  conv_bf16_k<<<(int)(nW / 4 / 256), 256, 0, stream>>>(w, Wb, (int)nW);
  rope_tab_k<<<(T_SEQ * 32) / 256, 256, 0, stream>>>(ctab, stab);

  // QKV GEMM (4096 x 3072 x 1024) with fused epilogue v2
  gemm_qkv_k<<<dim3(4096 / BM, 3072 / BN), 256, 0, stream>>>(Xb, Wb, ve, lam, ctab, stab,
                                                             Qb, Kb, Vt);

  attn_k<<<dim3(NBATCH * NH, 16), 512, 0, stream>>>(Qb, Kb, Vt, Yb);

  // out: (4096 x 1024) = Yb @ W3^T, f32 straight to d_out
  gemm_bt_k<float><<<dim3(4096 / BM, 1024 / BN), 256, 0, stream>>>(Yb, Wb + 3ull * DIMSZ * DIMSZ, out, 4096, 1024, 1024);
}

// Round 11
// 134.057 us; speedup vs baseline: 1.7585x; 1.0258x over previous
//
#include <hip/hip_runtime.h>
#include <hip/hip_bf16.h>
#include <stdint.h>

#define T_SEQ 2048
#define DIMSZ 1024
#define NH    16
#define HDIM  64
#define NBATCH 2
#define KVB   64
#define ATT_SCALE 0.12f
#define QSCALE (0.12f * 1.4426950408889634f)

typedef __attribute__((ext_vector_type(8))) __bf16 bf16x8;
typedef __attribute__((ext_vector_type(8))) ushort u16x8;
typedef __attribute__((ext_vector_type(4))) float f32x4;

#define GLOAD_LDS16(gp, lp)                                                            \
  __builtin_amdgcn_global_load_lds((const __attribute__((address_space(1))) void*)(gp),\
                                   (__attribute__((address_space(3))) void*)(lp),      \
                                   16, 0, 0)

__device__ __forceinline__ ushort f2bf(float f) {
  union { float f; uint32_t u; } v; v.f = f;
  uint32_t u = v.u;
  uint32_t r = (u + 0x7FFFu + ((u >> 16) & 1u)) >> 16;
  return (ushort)r;
}

__device__ __forceinline__ float bf2f(ushort h) {
  union { float f; uint32_t u; } v;
  v.u = ((uint32_t)h) << 16;
  return v.f;
}

// paired f32->bf16 (compiler fuses into v_cvt_pk_bf16_f32)
__device__ __forceinline__ uint32_t pk2(float a, float b) {
  union { __hip_bfloat162 h; uint32_t u; } cv;
  cv.h = __hip_bfloat162(__float2bfloat16(a), __float2bfloat16(b));
  return cv.u;
}

// ---------------- f32 -> bf16 convert (vectorized) ----------------
__global__ __launch_bounds__(256) void conv_bf16_k(const float* __restrict__ in,
                                                   ushort* __restrict__ out, int n) {
  int i = (blockIdx.x * 256 + threadIdx.x) * 4;
  if (i >= n) return;
  float4 v = *(const float4*)(in + i);
  ushort4 o;
  o.x = f2bf(v.x); o.y = f2bf(v.y); o.z = f2bf(v.z); o.w = f2bf(v.w);
  *(ushort4*)(out + i) = o;
}

// ---------------- RoPE tables: cos/sin (T x 32) ----------------
__global__ __launch_bounds__(256) void rope_tab_k(float* __restrict__ ctab,
                                                  float* __restrict__ stab) {
  int idx = blockIdx.x * 256 + threadIdx.x;  // t*32 + j
  if (idx >= T_SEQ * 32) return;
  int j = idx & 31, t = idx >> 5;
  float c = 1.f, s = 0.f;
  if (j < 16) {
    float inv = powf(1024.0f, -(float)j / 15.0f);  // (1/1024)^(j/15)
    float th = (float)t * inv;
    c = cosf(th);
    s = sinf(th);
  }
  ctab[idx] = c;
  stab[idx] = s;
}

// ---------------- bf16 GEMM 128^2 (out-projection) ----------------
#define BM 128
#define BN 128
#define BKS 64

template <typename OT>
__global__ __launch_bounds__(256) void gemm_bt_k(const ushort* __restrict__ A,
                                                 const ushort* __restrict__ Bt,
                                                 OT* __restrict__ C,
                                                 int M, int N, int K) {
  __shared__ __align__(16) ushort As[BM * BKS];
  __shared__ __align__(16) ushort Bs[BN * BKS];
  int tid = threadIdx.x;
  int wave = tid >> 6, lane = tid & 63;
  int lr = lane & 15, lg = lane >> 4;
  int m0 = blockIdx.x * BM, n0 = blockIdx.y * BN;
  int wm = (wave >> 1) * 64, wn = (wave & 1) * 64;

  f32x4 acc[4][4];
  for (int m = 0; m < 4; ++m)
    for (int n = 0; n < 4; ++n)
      acc[m][n] = (f32x4){0.f, 0.f, 0.f, 0.f};

  for (int k0 = 0; k0 < K; k0 += BKS) {
#pragma unroll
    for (int it = 0; it < 4; ++it) {
      int idx = it * 256 + tid;        // 16B chunk id, 1024 total
      int row = idx >> 3;              // 8 chunks per 64-elem row
      int col = (idx & 7) * 8;
      GLOAD_LDS16(A + (size_t)(m0 + row) * K + k0 + col, &As[idx * 8]);
      GLOAD_LDS16(Bt + (size_t)(n0 + row) * K + k0 + col, &Bs[idx * 8]);
    }
    __syncthreads();
#pragma unroll
    for (int kk = 0; kk < 2; ++kk) {
      bf16x8 af[4], bf[4];
#pragma unroll
      for (int m = 0; m < 4; ++m)
        af[m] = *(const bf16x8*)&As[(wm + m * 16 + lr) * BKS + kk * 32 + lg * 8];
#pragma unroll
      for (int n = 0; n < 4; ++n)
        bf[n] = *(const bf16x8*)&Bs[(wn + n * 16 + lr) * BKS + kk * 32 + lg * 8];
#pragma unroll
      for (int m = 0; m < 4; ++m)
#pragma unroll
        for (int n = 0; n < 4; ++n)
          acc[m][n] = __builtin_amdgcn_mfma_f32_16x16x32_bf16(af[m], bf[n], acc[m][n], 0, 0, 0);
    }
    __syncthreads();
  }
#pragma unroll
  for (int m = 0; m < 4; ++m)
#pragma unroll
    for (int n = 0; n < 4; ++n)
#pragma unroll
      for (int r = 0; r < 4; ++r) {
        int row = m0 + wm + m * 16 + lg * 4 + r;
        int col = n0 + wn + n * 16 + lr;
        if constexpr (sizeof(OT) == 2)
          C[(size_t)row * N + col] = (OT)f2bf(acc[m][n][r]);
        else
          C[(size_t)row * N + col] = (OT)acc[m][n][r];
      }
}

// ---------------- QKV GEMM: 256^2 tile, 8 waves, dbuf LDS, XOR-swizzled ----------------
// Theory (R10 counters): the 128^2 loop is LDS-read-bound: unswizzled b128 reads pack
// 16 lanes/bank-slot (floor is 8) -> 2x LDS cost; 9.5M conflict cycles/dispatch.
// This kernel: (a) XOR-swizzle slot = chunk ^ (row&7) via pre-swizzled global source
// (m173 pattern; proven in attn_k) -> reads at the 8-lane floor; (b) 256^2 tile,
// 8 waves of 128x64 -> 25% fewer LDS bytes/MFMA, 2x fewer staged bytes/FLOP;
// (c) explicit double-buffer: stage k+1 issued BEFORE compute k, drained by the
// barrier after compute (attn_k's proven loop shape). 1 block/CU (128KB LDS).
// Epilogue: v2 token-ownership, run per 64-token half in the wave's 8KB LDS slice.
#define BM2 256
#define BN2 256

__global__ __launch_bounds__(512, 2) void gemm_qkv_k(const ushort* __restrict__ A,
                                                     const ushort* __restrict__ Bt,
                                                     const float* __restrict__ ve,
                                                     const float* __restrict__ lam,
                                                     const float* __restrict__ ctab,
                                                     const float* __restrict__ stab,
                                                     ushort* __restrict__ Qb,
                                                     ushort* __restrict__ Kb,
                                                     ushort* __restrict__ Vt) {
  const int K = DIMSZ;
  __shared__ __align__(16) ushort As[2][BM2 * BKS];  // 2 x 32KB
  __shared__ __align__(16) ushort Bs[2][BN2 * BKS];  // 2 x 32KB
  int tid = threadIdx.x;
  int wid = tid >> 6, lane = tid & 63;
  int lr = lane & 15, lg = lane >> 4;
  int m0 = blockIdx.x * BM2, n0 = blockIdx.y * BN2;
  int wm = (wid >> 2) * 128, wn = (wid & 3) * 64;

  // staging map: thread -> (row = it*64 + tid>>3, slot = tid&7); the slot holds
  // logical chunk (slot ^ (row&7)) -> pre-swizzle the GLOBAL column, LDS stays linear
  int srow = tid >> 3;
  int sel = (((tid & 7) ^ (srow & 7)) << 3);
  const ushort* aSrc = A + (size_t)(m0 + srow) * K + sel;
  const ushort* bSrc = Bt + (size_t)(n0 + srow) * K + sel;
  int dstoff = tid * 8;  // elements; + it*4096

  f32x4 acc[8][4];
#pragma unroll
  for (int m = 0; m < 8; ++m)
#pragma unroll
    for (int n = 0; n < 4; ++n)
      acc[m][n] = (f32x4){0.f, 0.f, 0.f, 0.f};

  // prologue: stage K-step 0 into buffer 0
#pragma unroll
  for (int it = 0; it < 4; ++it) {
    GLOAD_LDS16(aSrc + (size_t)it * 64 * K, &As[0][it * 4096 + dstoff]);
    GLOAD_LDS16(bSrc + (size_t)it * 64 * K, &Bs[0][it * 4096 + dstoff]);
  }
  __syncthreads();

  int rs = lr & 7;
  int cur = 0;
  for (int ks = 0; ks < 16; ++ks) {
    if (ks + 1 < 16) {
      int k0 = (ks + 1) * BKS;
#pragma unroll
      for (int it = 0; it < 4; ++it) {
        GLOAD_LDS16(aSrc + (size_t)it * 64 * K + k0, &As[cur ^ 1][it * 4096 + dstoff]);
        GLOAD_LDS16(bSrc + (size_t)it * 64 * K + k0, &Bs[cur ^ 1][it * 4096 + dstoff]);
      }
    }
    const ushort* Ac = &As[cur][0];
    const ushort* Bc = &Bs[cur][0];
#pragma unroll
    for (int kk = 0; kk < 2; ++kk) {
      int cA = (((kk * 4 + lg) ^ rs) << 3);
      bf16x8 af[8], bfr[4];
#pragma unroll
      for (int m = 0; m < 8; ++m)
        af[m] = *(const bf16x8*)&Ac[(wm + m * 16 + lr) * 64 + cA];
#pragma unroll
      for (int n = 0; n < 4; ++n)
        bfr[n] = *(const bf16x8*)&Bc[(wn + n * 16 + lr) * 64 + cA];
#pragma unroll
      for (int m = 0; m < 8; ++m)
#pragma unroll
        for (int n = 0; n < 4; ++n)
          acc[m][n] = __builtin_amdgcn_mfma_f32_16x16x32_bf16(af[m], bfr[n], acc[m][n], 0, 0, 0);
    }
    __syncthreads();  // staging (vmcnt) drained + buf[cur] consumed by all
    cur ^= 1;
  }

  // ---- fused epilogue (token-ownership), two 64-token halves ----
  int sec = n0 >> 10;                   // 0=Q, 1=K, 2=V (block-uniform; 256 | 1024)
  int h = ((n0 & 1023) + wn) >> 6;      // head (wave-uniform)
  ushort* Tl = &As[0][0] + wid * 4096;  // 8KB slice per wave (spans As[0..1], all dead)
  float l0 = lam[0], l1 = lam[1];

#pragma unroll
  for (int hf = 0; hf < 2; ++hf) {
    // write 4 m-fragments (64 tokens x 64 dims) bf16, dim-chunk XOR-swizzled
#pragma unroll
    for (int mi = 0; mi < 4; ++mi)
#pragma unroll
      for (int n = 0; n < 4; ++n)
#pragma unroll
        for (int r = 0; r < 4; ++r) {
          int tl = mi * 16 + lg * 4 + r;
          int d = n * 16 + lr;
          Tl[tl * 64 + ((((d >> 3) ^ (tl & 7)) << 3) | (d & 7))] = f2bf(acc[hf * 4 + mi][n][r]);
        }
    // each lane reads its own token row
    int tl = lane;
    float xv[64];
#pragma unroll
    for (int j = 0; j < 8; ++j) {
      u16x8 rw = *(const u16x8*)&Tl[tl * 64 + ((j ^ (tl & 7)) << 3)];
#pragma unroll
      for (int e = 0; e < 8; ++e) xv[j * 8 + e] = bf2f((ushort)rw[e]);
    }
    // RMSNorm in-lane
    float ss = 0.f;
#pragma unroll
    for (int i = 0; i < 64; ++i) ss += xv[i] * xv[i];
    float rinv = rsqrtf(ss * (1.0f / 64.0f) + 1e-6f);
#pragma unroll
    for (int i = 0; i < 64; ++i) xv[i] *= rinv;

    int row = m0 + wm + hf * 64 + tl;   // token id 0..4095
    int t = row & (T_SEQ - 1);
    int bb = row >> 11;
    int bh = bb * NH + h;

    if (sec < 2) {
      // RoPE in-lane: pairs (j, j+32)
      float cs[16], sn[16];
      const float4* cp = (const float4*)(ctab + t * 32);
      const float4* sp = (const float4*)(stab + t * 32);
#pragma unroll
      for (int j = 0; j < 4; ++j) {
        float4 c4 = cp[j], s4 = sp[j];
        cs[j * 4 + 0] = c4.x; cs[j * 4 + 1] = c4.y; cs[j * 4 + 2] = c4.z; cs[j * 4 + 3] = c4.w;
        sn[j * 4 + 0] = s4.x; sn[j * 4 + 1] = s4.y; sn[j * 4 + 2] = s4.z; sn[j * 4 + 3] = s4.w;
      }
#pragma unroll
      for (int j = 0; j < 16; ++j) {
        float a = xv[j], bv = xv[j + 32];
        xv[j] = a * cs[j] + bv * sn[j];
        xv[j + 32] = bv * cs[j] - a * sn[j];
      }
      float sc = (sec == 0) ? QSCALE : 1.0f;
      ushort* dst = (sec == 0 ? Qb : Kb) + ((size_t)bh * T_SEQ + t) * HDIM;
#pragma unroll
      for (int p = 0; p < 8; ++p) {
        uint4 wq = make_uint4(pk2(xv[8 * p] * sc, xv[8 * p + 1] * sc),
                              pk2(xv[8 * p + 2] * sc, xv[8 * p + 3] * sc),
                              pk2(xv[8 * p + 4] * sc, xv[8 * p + 5] * sc),
                              pk2(xv[8 * p + 6] * sc, xv[8 * p + 7] * sc));
        *((uint4*)dst + p) = wq;
      }
    } else {
      const float4* vp = (const float4*)(ve + ((size_t)(bb * T_SEQ + t)) * DIMSZ + h * HDIM);
#pragma unroll
      for (int j = 0; j < 16; ++j) {
        float4 vv4 = vp[j];
        xv[j * 4 + 0] = l0 * xv[j * 4 + 0] + l1 * vv4.x;
        xv[j * 4 + 1] = l0 * xv[j * 4 + 1] + l1 * vv4.y;
        xv[j * 4 + 2] = l0 * xv[j * 4 + 2] + l1 * vv4.z;
        xv[j * 4 + 3] = l0 * xv[j * 4 + 3] + l1 * vv4.w;
      }
      ushort* dst = Vt + (size_t)bh * HDIM * T_SEQ + t;
#pragma unroll
      for (int i = 0; i < 64; ++i)
        dst[(size_t)i * T_SEQ] = f2bf(xv[i]);
    }
  }
}

// ---------------- flash attention: LDS-shared K/V, dual-tile blocks (unchanged) ----
__global__ __launch_bounds__(512, 4) void attn_k(const ushort* __restrict__ Q,
                                                 const ushort* __restrict__ K,
                                                 const ushort* __restrict__ Vt,
                                                 ushort* __restrict__ Y) {
  int bh = blockIdx.x;    // 0..31 -> dispatch id % 8 = bh % 8 (XCD L2 locality)
  int pair = blockIdx.y;  // 0..15, heavy (pair=0 -> 32 tiles) first
  int tid = threadIdx.x;
  int wid = tid >> 6, lane = tid & 63;
  int lr = lane & 15, lg = lane >> 4;
  int b = bh >> 4, h = bh & 15;

  int NT = 32 - pair;                    // staged KV tiles: kb = 0..NT-1
  int grp = wid >> 2;                    // 0 -> tile pair, 1 -> tile 31-pair
  int myqb = grp ? (31 - pair) : pair;
  int mylast = grp ? (NT - 1) : pair;    // my diagonal (and last active) iter
  int strip = wid & 3;
  int r0 = myqb * 64 + strip * 16;

  __shared__ __align__(16) ushort Kl[2][KVB * HDIM];   // 2 x 8 KB
  __shared__ __align__(16) ushort Vl[2][KVB * HDIM];   // 2 x 8 KB ([d=64][key=64])
  __shared__ __align__(16) ushort Plds[8][16][72];

  const ushort* Kbh = K + (size_t)bh * T_SEQ * HDIM;
  const ushort* Vbh = Vt + (size_t)bh * HDIM * T_SEQ;

  // staging: thread t -> LDS (row = t>>3, 16B-chunk = t&7); source pre-swizzled
  int srow = tid >> 3, schunk = tid & 7;
  int sel = ((schunk ^ (srow & 7)) << 3);                 // element offset in 64-elem row
  const ushort* ksrc = Kbh + (size_t)srow * HDIM + sel;   // + kb*KVB*HDIM
  const ushort* vsrc = Vbh + (size_t)srow * T_SEQ + sel;  // + kb*KVB
  int ldst = wid << 9;                                    // wave-uniform LDS base (elems)

  // Q fragments (global, read once)
  const ushort* Qbase = Q + ((size_t)bh * T_SEQ + r0) * HDIM;
  bf16x8 aq[2];
#pragma unroll
  for (int kk = 0; kk < 2; ++kk)
    aq[kk] = *(const bf16x8*)(Qbase + (size_t)lr * HDIM + kk * 32 + lg * 8);

  // swizzled fragment column offsets (element units)
  int fcol[2];
  fcol[0] = ((0 + lg) ^ (lr & 7)) << 3;
  fcol[1] = ((4 + lg) ^ (lr & 7)) << 3;

  f32x4 o[4];
#pragma unroll
  for (int n = 0; n < 4; ++n) o[n] = (f32x4){0.f, 0.f, 0.f, 0.f};
  float lrow = 0.f;

  // prologue: stage tile 0 into buffer 0
  GLOAD_LDS16(ksrc, &Kl[0][ldst]);
  GLOAD_LDS16(vsrc, &Vl[0][ldst]);
  __syncthreads();

  int cur = 0;
  for (int kb = 0; kb < NT; ++kb) {
    // issue next tile's staging first (latency hides under compute)
    if (kb + 1 < NT) {
      GLOAD_LDS16(ksrc + (size_t)(kb + 1) * KVB * HDIM, &Kl[cur ^ 1][ldst]);
      GLOAD_LDS16(vsrc + (kb + 1) * KVB, &Vl[cur ^ 1][ldst]);
    }
    if (kb <= mylast) {
      const ushort* Kc = &Kl[cur][0];
      const ushort* Vc = &Vl[cur][0];
      // S^T = K . Q^T : lane holds S[q=r0+lr][key = kb*64 + n*16 + lg*4 + r]
      f32x4 s[4];
#pragma unroll
      for (int n = 0; n < 4; ++n) {
        f32x4 a = (f32x4){0.f, 0.f, 0.f, 0.f};
        bf16x8 kf0 = *(const bf16x8*)&Kc[(n * 16 + lr) * HDIM + fcol[0]];
        a = __builtin_amdgcn_mfma_f32_16x16x32_bf16(kf0, aq[0], a, 0, 0, 0);
        bf16x8 kf1 = *(const bf16x8*)&Kc[(n * 16 + lr) * HDIM + fcol[1]];
        a = __builtin_amdgcn_mfma_f32_16x16x32_bf16(kf1, aq[1], a, 0, 0, 0);
        s[n] = a;
      }
      // causal mask on my diagonal tile
      if (kb == mylast) {
        int qrow = r0 + lr;
        int kb0 = kb * KVB + lg * 4;
#pragma unroll
        for (int n = 0; n < 4; ++n)
#pragma unroll
          for (int r = 0; r < 4; ++r)
            if (kb0 + n * 16 + r > qrow) s[n][r] = -1e30f;
      }
      // P = exp2(S) (static shift: |arg| <= 11.08 after RMSNorm); lane-partial sum
      float psum = 0.f;
#pragma unroll
      for (int n = 0; n < 4; ++n) {
        float p0 = exp2f(s[n][0]), p1 = exp2f(s[n][1]);
        float p2 = exp2f(s[n][2]), p3 = exp2f(s[n][3]);
        psum += (p0 + p1) + (p2 + p3);
        uint2 w;
        w.x = pk2(p0, p1);
        w.y = pk2(p2, p3);
        *(uint2*)&Plds[wid][lr][n * 16 + lg * 4] = w;
      }
      lrow += psum;
      // PV: O^T += V^T . P^T
#pragma unroll
      for (int kk = 0; kk < 2; ++kk) {
        bf16x8 ap = *(const bf16x8*)&Plds[wid][lr][kk * 32 + lg * 8];
#pragma unroll
        for (int n = 0; n < 4; ++n) {
          bf16x8 vf = *(const bf16x8*)&Vc[(n * 16 + lr) * HDIM + fcol[kk]];
          o[n] = __builtin_amdgcn_mfma_f32_16x16x32_bf16(vf, ap, o[n], 0, 0, 0);
        }
      }
    }
    __syncthreads();  // staging landed (vmcnt 0) + buf[cur] consumed by all
    cur ^= 1;
  }
  // epilogue: complete row sum across lg groups, normalize, write
  lrow += __shfl_xor(lrow, 16);
  lrow += __shfl_xor(lrow, 32);
  float inv = 1.0f / lrow;
  int row = r0 + lr;
#pragma unroll
  for (int n = 0; n < 4; ++n) {
    uint2 w;
    w.x = pk2(o[n][0] * inv, o[n][1] * inv);
    w.y = pk2(o[n][2] * inv, o[n][3] * inv);
    *(uint2*)&Y[((size_t)b * T_SEQ + row) * DIMSZ + h * HDIM + n * 16 + lg * 4] = w;
  }
}

// ---------------- launch ----------------
extern "C" void kernel_launch(void* const* d_in, const int* in_sizes, int n_in,
                              void* d_out, int out_size, void* d_ws, size_t ws_size,
                              hipStream_t stream) {
  const float* x   = (const float*)d_in[0];
  const float* ve  = (const float*)d_in[1];
  const float* lam = (const float*)d_in[2];
  const float* w   = (const float*)d_in[4];  // (4, 1024, 1024)
  float* out = (float*)d_out;

  char* ws = (char*)d_ws;
  const size_t NTOK = (size_t)NBATCH * T_SEQ;          // 4096
  const size_t nX = NTOK * DIMSZ;                      // 4,194,304
  const size_t nW = 4ull * DIMSZ * DIMSZ;              // 4,194,304

  ushort* Xb   = (ushort*)(ws);                        // 8 MB  @ 0
  ushort* Wb   = (ushort*)(ws + 8388608);              // 8 MB  @ 8M
  ushort* Qb   = (ushort*)(ws + 16777216);             // 8 MB  @ 16M
  ushort* Kb   = (ushort*)(ws + 25165824);             // 8 MB  @ 24M
  ushort* Vt   = (ushort*)(ws + 33554432);             // 8 MB  @ 32M
  ushort* Yb   = (ushort*)(ws + 41943040);             // 8 MB  @ 40M
  float*  ctab = (float*)(ws + 50331648);              // 256 KB @ 48M
  float*  stab = (float*)(ws + 50593792);              // 256 KB

  conv_bf16_k<<<(int)(nX / 4 / 256), 256, 0, stream>>>(x, Xb, (int)nX);
  conv_bf16_k<<<(int)(nW / 4 / 256), 256, 0, stream>>>(w, Wb, (int)nW);
  rope_tab_k<<<(T_SEQ * 32) / 256, 256, 0, stream>>>(ctab, stab);

  // QKV GEMM (4096 x 3072 x 1024), 256^2 tiles, fused epilogue
  gemm_qkv_k<<<dim3(4096 / BM2, 3072 / BN2), 512, 0, stream>>>(Xb, Wb, ve, lam, ctab, stab,
                                                               Qb, Kb, Vt);

  attn_k<<<dim3(NBATCH * NH, 16), 512, 0, stream>>>(Qb, Kb, Vt, Yb);

  // out: (4096 x 1024) = Yb @ W3^T, f32 straight to d_out
  gemm_bt_k<float><<<dim3(4096 / BM, 1024 / BN), 256, 0, stream>>>(Yb, Wb + 3ull * DIMSZ * DIMSZ, out, 4096, 1024, 1024);
}